// Round 1
// baseline (1994.535 us; speedup 1.0000x reference)
//
#include <hip/hip_runtime.h>
#include <float.h>
#include <math.h>

#define BS 4
#define V1 2048
#define V2 1024
#define NB 20
#define KSEL 21   // k+1: take 21 nearest, drop the nearest (self)

// ---------------- kNN: one block per (b, row). dist in LDS, 21x masked argmin ----------------
__global__ __launch_bounds__(256)
void knn_kernel(const float* __restrict__ verts, int Vv, int stride, int* __restrict__ nbr)
{
    __shared__ float dist[V1];
    __shared__ unsigned long long red[4];
    __shared__ int winners[KSEL];
    int bi = blockIdx.x;
    int b = bi / Vv, i = bi % Vv;
    const float* vb = verts + (size_t)b * V1 * 3;
    int tid = threadIdx.x;
    float xi = vb[(size_t)i * stride * 3 + 0];
    float yi = vb[(size_t)i * stride * 3 + 1];
    float zi = vb[(size_t)i * stride * 3 + 2];
    float sqi = xi * xi + yi * yi + zi * zi;
    for (int j = tid; j < Vv; j += 256) {
        float xj = vb[(size_t)j * stride * 3 + 0];
        float yj = vb[(size_t)j * stride * 3 + 1];
        float zj = vb[(size_t)j * stride * 3 + 2];
        float sqj = xj * xj + yj * yj + zj * zj;
        float dt = xi * xj + yi * yj + zi * zj;
        dist[j] = sqi - 2.0f * dt + sqj;   // matches ref: sq_i - 2*inner + sq_j
    }
    __syncthreads();
    for (int s = 0; s < KSEL; ++s) {
        unsigned long long best = ~0ull;
        for (int j = tid; j < Vv; j += 256) {
            unsigned u = __float_as_uint(dist[j]);
            u = (u & 0x80000000u) ? ~u : (u | 0x80000000u);   // monotonic float->uint
            unsigned long long key = ((unsigned long long)u << 32) | (unsigned)j;
            if (key < best) best = key;
        }
        #pragma unroll
        for (int off = 32; off > 0; off >>= 1) {
            unsigned long long o = __shfl_down(best, off);   // wave64
            if (o < best) best = o;
        }
        if ((tid & 63) == 0) red[tid >> 6] = best;
        __syncthreads();
        if (tid == 0) {
            unsigned long long r = red[0];
            if (red[1] < r) r = red[1];
            if (red[2] < r) r = red[2];
            if (red[3] < r) r = red[3];
            int widx = (int)(r & 0xffffffffull);
            winners[s] = widx;
            dist[widx] = FLT_MAX;
        }
        __syncthreads();
    }
    if (tid < NB) nbr[((size_t)b * Vv + i) * NB + tid] = winners[tid + 1];
}

// ---------------- normalized neighbor difference vectors ----------------
__global__ __launch_bounds__(256)
void diffn_kernel(const float* __restrict__ verts, const int* __restrict__ nbr,
                  int Vv, int stride, float* __restrict__ diffn)
{
    int t = blockIdx.x * 256 + threadIdx.x;
    int total = BS * Vv * NB;
    if (t >= total) return;
    int v = (t / NB) % Vv;
    int b = t / (NB * Vv);
    const float* vb = verts + (size_t)b * V1 * 3;
    int j = nbr[t];
    float xi = vb[(size_t)v * stride * 3 + 0];
    float yi = vb[(size_t)v * stride * 3 + 1];
    float zi = vb[(size_t)v * stride * 3 + 2];
    float dx = vb[(size_t)j * stride * 3 + 0] - xi;
    float dy = vb[(size_t)j * stride * 3 + 1] - yi;
    float dz = vb[(size_t)j * stride * 3 + 2] - zi;
    float nrm = sqrtf(dx * dx + dy * dy + dz * dz);
    float inv = 1.0f / fmaxf(nrm, 1e-12f);
    diffn[(size_t)t * 3 + 0] = dx * inv;
    diffn[(size_t)t * 3 + 1] = dy * inv;
    diffn[(size_t)t * 3 + 2] = dz * inv;
}

// ---------------- fp32 tiled GEMM + bias: C(MxN) = A(MxK) @ W(KxN) + bias ----------------
template<int BM, int BN, int BK, int TM, int TN>
__global__ __launch_bounds__(256)
void gemm_bias(const float* __restrict__ A, const float* __restrict__ W,
               const float* __restrict__ bias, float* __restrict__ C,
               int M, int N, int K)
{
    __shared__ float As[BK][BM + 4];
    __shared__ float Bs[BK][BN + 4];
    constexpr int TX = BN / TN;
    int tid = threadIdx.x;
    int tx = tid % TX, ty = tid / TX;
    int m0 = blockIdx.y * BM, n0 = blockIdx.x * BN;
    float acc[TM][TN];
    #pragma unroll
    for (int i = 0; i < TM; ++i)
        #pragma unroll
        for (int j = 0; j < TN; ++j) acc[i][j] = 0.0f;

    for (int k0 = 0; k0 < K; k0 += BK) {
        for (int i = tid; i < BM * BK; i += 256) {
            int m = i / BK, k = i % BK;
            float v = 0.0f;
            if (k0 + k < K) v = A[(size_t)(m0 + m) * K + k0 + k];
            As[k][m] = v;
        }
        for (int i = tid; i < BN * BK; i += 256) {
            int n = i % BN, k = i / BN;
            float v = 0.0f;
            if (k0 + k < K) v = W[(size_t)(k0 + k) * N + n0 + n];
            Bs[k][n] = v;
        }
        __syncthreads();
        #pragma unroll
        for (int k = 0; k < BK; ++k) {
            float a[TM], bb[TN];
            #pragma unroll
            for (int i = 0; i < TM; ++i) a[i] = As[k][ty * TM + i];
            #pragma unroll
            for (int j = 0; j < TN; ++j) bb[j] = Bs[k][tx * TN + j];
            #pragma unroll
            for (int i = 0; i < TM; ++i)
                #pragma unroll
                for (int j = 0; j < TN; ++j)
                    acc[i][j] = fmaf(a[i], bb[j], acc[i][j]);
        }
        __syncthreads();
    }
    #pragma unroll
    for (int i = 0; i < TM; ++i) {
        int mm = m0 + ty * TM + i;
        #pragma unroll
        for (int j = 0; j < TN; ++j) {
            int nn = n0 + tx * TN + j;
            C[(size_t)mm * N + nn] = acc[i][j] + bias[nn];
        }
    }
}

// ---------------- act epilogue: out = center + max_n(theta * support) ----------------
__global__ __launch_bounds__(256)
void act_kernel(const float* __restrict__ feat, const int* __restrict__ nbr,
                const float* __restrict__ diffn, const float* __restrict__ dmat,
                float* __restrict__ outp, int Vv, int OC)
{
    int OC4 = OC >> 2;
    int t = blockIdx.x * 256 + threadIdx.x;
    int total = BS * Vv * OC4;
    if (t >= total) return;
    int c4 = t % OC4;
    int v = (t / OC4) % Vv;
    int b = t / (OC4 * Vv);
    const float4* d4 = (const float4*)dmat;
    float4 D0 = d4[c4], D1 = d4[OC4 + c4], D2 = d4[2 * OC4 + c4];
    // normalize direction columns: d / max(||d||_col, 1e-12)
    float n0 = sqrtf(D0.x * D0.x + D1.x * D1.x + D2.x * D2.x);
    float n1 = sqrtf(D0.y * D0.y + D1.y * D1.y + D2.y * D2.y);
    float n2 = sqrtf(D0.z * D0.z + D1.z * D1.z + D2.z * D2.z);
    float n3 = sqrtf(D0.w * D0.w + D1.w * D1.w + D2.w * D2.w);
    float i0 = 1.0f / fmaxf(n0, 1e-12f);
    float i1 = 1.0f / fmaxf(n1, 1e-12f);
    float i2 = 1.0f / fmaxf(n2, 1e-12f);
    float i3 = 1.0f / fmaxf(n3, 1e-12f);
    D0.x *= i0; D0.y *= i1; D0.z *= i2; D0.w *= i3;
    D1.x *= i0; D1.y *= i1; D1.z *= i2; D1.w *= i3;
    D2.x *= i0; D2.y *= i1; D2.z *= i2; D2.w *= i3;

    const int* nb = nbr + ((size_t)b * Vv + v) * NB;
    const float* dfn = diffn + ((size_t)b * Vv + v) * NB * 3;
    const float4* frow = (const float4*)feat;
    size_t rowstride = (size_t)(2 * OC4);
    const float4* fsup = frow + (size_t)b * Vv * rowstride + OC4 + c4;
    float4 m = make_float4(-FLT_MAX, -FLT_MAX, -FLT_MAX, -FLT_MAX);
    for (int n = 0; n < NB; ++n) {
        int idx = nb[n];
        float e0 = dfn[3 * n + 0], e1 = dfn[3 * n + 1], e2 = dfn[3 * n + 2];
        float4 s = fsup[(size_t)idx * rowstride];
        float th;
        th = e0 * D0.x + e1 * D1.x + e2 * D2.x; m.x = fmaxf(m.x, th * s.x);
        th = e0 * D0.y + e1 * D1.y + e2 * D2.y; m.y = fmaxf(m.y, th * s.y);
        th = e0 * D0.z + e1 * D1.z + e2 * D2.z; m.z = fmaxf(m.z, th * s.z);
        th = e0 * D0.w + e1 * D1.w + e2 * D2.w; m.w = fmaxf(m.w, th * s.w);
    }
    float4 cen = frow[(size_t)b * Vv * rowstride + (size_t)v * rowstride + c4];
    float4 r = make_float4(cen.x + m.x, cen.y + m.y, cen.z + m.z, cen.w + m.w);
    ((float4*)outp)[((size_t)b * Vv + v) * OC4 + c4] = r;
}

// ---------------- neighbor max-pool + stride-2 subsample (64 channels) ----------------
__global__ __launch_bounds__(256)
void pool_kernel(const float4* __restrict__ fm, const int* __restrict__ nbr,
                 float4* __restrict__ outp)
{
    const int C4 = 16;   // 64/4
    int t = blockIdx.x * 256 + threadIdx.x;
    int total = BS * V2 * C4;
    if (t >= total) return;
    int c = t % C4;
    int v2 = (t / C4) % V2;
    int b = t / (C4 * V2);
    const int* nb = nbr + ((size_t)b * V1 + 2 * v2) * NB;
    float4 m = make_float4(-FLT_MAX, -FLT_MAX, -FLT_MAX, -FLT_MAX);
    for (int n = 0; n < NB; ++n) {
        int idx = nb[n];
        float4 s = fm[((size_t)b * V1 + idx) * C4 + c];
        m.x = fmaxf(m.x, s.x); m.y = fmaxf(m.y, s.y);
        m.z = fmaxf(m.z, s.z); m.w = fmaxf(m.w, s.w);
    }
    outp[((size_t)b * V2 + v2) * C4 + c] = m;
}

// ---------------- global max over vertices (two stage) ----------------
__global__ __launch_bounds__(256)
void gmax_part(const float* __restrict__ fm, float* __restrict__ part)
{
    int c = blockIdx.x * 256 + threadIdx.x;   // 0..1023
    int ch = blockIdx.y;                      // 0..7
    int b = blockIdx.z;
    float m = -FLT_MAX;
    for (int v = ch * 128; v < (ch + 1) * 128; ++v)
        m = fmaxf(m, fm[((size_t)b * V2 + v) * 1024 + c]);
    part[((size_t)b * 8 + ch) * 1024 + c] = m;
}

__global__ __launch_bounds__(256)
void gmax_final(const float* __restrict__ part, float* __restrict__ g)
{
    int t = blockIdx.x * 256 + threadIdx.x;
    if (t >= BS * 1024) return;
    int c = t % 1024, b = t / 1024;
    float m = -FLT_MAX;
    for (int ch = 0; ch < 8; ++ch)
        m = fmaxf(m, part[((size_t)b * 8 + ch) * 1024 + c]);
    g[t] = m;
}

// ---------------- head: fc1 + bn + relu + fc2 ----------------
__global__ __launch_bounds__(256)
void head_kernel(const float* __restrict__ g, const float* __restrict__ fc1w,
                 const float* __restrict__ fc1b, const float* __restrict__ bng,
                 const float* __restrict__ bnb, const float* __restrict__ fc2w,
                 const float* __restrict__ fc2b, float* __restrict__ outp)
{
    __shared__ float gs[1024];
    __shared__ float hs[256];
    int b = blockIdx.x;
    int j = threadIdx.x;
    for (int k = j; k < 1024; k += 256) gs[k] = g[(size_t)b * 1024 + k];
    __syncthreads();
    float h = fc1b[j];
    for (int k = 0; k < 1024; ++k) h = fmaf(gs[k], fc1w[(size_t)k * 256 + j], h);
    const float rc = 0.99999500003749937f;   // rsqrt(1 + 1e-5)
    h = h * rc * bng[j] + bnb[j];
    h = fmaxf(h, 0.0f);
    hs[j] = h;
    __syncthreads();
    if (j < 40) {
        float o = fc2b[j];
        for (int k = 0; k < 256; ++k) o = fmaf(hs[k], fc2w[(size_t)k * 40 + j], o);
        outp[(size_t)b * 40 + j] = o;
    }
}

// ---------------- host driver ----------------
extern "C" void kernel_launch(void* const* d_in, const int* in_sizes, int n_in,
                              void* d_out, int out_size, void* d_ws, size_t ws_size,
                              hipStream_t stream)
{
    (void)in_sizes; (void)n_in; (void)out_size; (void)ws_size;
    const float* verts = (const float*)d_in[0];
    auto Wp = [&](int i) { return (const float*)d_in[1 + 3 * i]; };
    auto Bp = [&](int i) { return (const float*)d_in[2 + 3 * i]; };
    auto Dp = [&](int i) { return (const float*)d_in[3 + 3 * i]; };
    const float* fc1w = (const float*)d_in[37];
    const float* fc1b = (const float*)d_in[38];
    const float* bng  = (const float*)d_in[39];
    const float* bnb  = (const float*)d_in[40];
    const float* fc2w = (const float*)d_in[41];
    const float* fc2b = (const float*)d_in[42];

    static const int IC[12] = {3, 32, 64, 64, 64, 64, 64, 128, 256, 1024, 1024, 1024};
    static const int OC[12] = {32, 64, 64, 64, 64, 64, 128, 256, 1024, 1024, 1024, 1024};

    char* ws = (char*)d_ws;
    size_t off = 0;
    auto alloc = [&](size_t bytes) {
        void* p = ws + off;
        off += (bytes + 255) & ~(size_t)255;
        return p;
    };
    int*   nbr1   = (int*)alloc((size_t)BS * V1 * NB * 4);
    int*   nbr2   = (int*)alloc((size_t)BS * V2 * NB * 4);
    float* diffn1 = (float*)alloc((size_t)BS * V1 * NB * 3 * 4);
    float* diffn2 = (float*)alloc((size_t)BS * V2 * NB * 3 * 4);
    float* fm0    = (float*)alloc((size_t)BS * V2 * 1024 * 4);   // 16.8 MB
    float* fm1    = (float*)alloc((size_t)BS * V2 * 1024 * 4);   // 16.8 MB
    float* feat   = (float*)alloc((size_t)BS * V2 * 2048 * 4);   // 33.5 MB
    float* gpart  = (float*)alloc((size_t)BS * 8 * 1024 * 4);
    float* g      = (float*)alloc((size_t)BS * 1024 * 4);
    // note: full-res fm needs only BS*V1*64*4 = 2.1 MB < fm buffer size. feat full-res
    // needs BS*V1*128*4 = 4.2 MB < 33.5 MB. All fits.

    auto gemm = [&](const float* A, const float* w, const float* bias, float* Cc,
                    int M, int N, int K) {
        if (N >= 1024) {
            dim3 gdim(N / 128, M / 128);
            gemm_bias<128, 128, 16, 8, 8><<<gdim, 256, 0, stream>>>(A, w, bias, Cc, M, N, K);
        } else {
            dim3 gdim(N / 64, M / 64);
            gemm_bias<64, 64, 16, 4, 4><<<gdim, 256, 0, stream>>>(A, w, bias, Cc, M, N, K);
        }
    };
    auto act = [&](const float* f, const int* nbr, const float* dfn, const float* d,
                   float* outp, int Vv, int oc) {
        int total = BS * Vv * (oc / 4);
        act_kernel<<<(total + 255) / 256, 256, 0, stream>>>(f, nbr, dfn, d, outp, Vv, oc);
    };

    // ---- stage 1: full-res kNN + diffs ----
    knn_kernel<<<BS * V1, 256, 0, stream>>>(verts, V1, 1, nbr1);
    diffn_kernel<<<(BS * V1 * NB + 255) / 256, 256, 0, stream>>>(verts, nbr1, V1, 1, diffn1);

    // ---- full-res conv layers (c0, c1, c12, c13, c14, p1) ----
    const float* cur = verts;
    float* fmb[2] = {fm0, fm1};
    int pb = 0;
    for (int i = 0; i < 6; ++i) {
        gemm(cur, Wp(i), Bp(i), feat, BS * V1, 2 * OC[i], IC[i]);
        float* o = fmb[pb]; pb ^= 1;
        act(feat, nbr1, diffn1, Dp(i), o, V1, OC[i]);
        cur = o;
    }

    // ---- pool (neighbor max at full res, subsample stride 2) ----
    {
        float* o = fmb[pb]; pb ^= 1;
        int total = BS * V2 * 16;
        pool_kernel<<<(total + 255) / 256, 256, 0, stream>>>((const float4*)cur, nbr1, (float4*)o);
        cur = o;
    }

    // ---- stage 2: half-res kNN + diffs ----
    knn_kernel<<<BS * V2, 256, 0, stream>>>(verts, V2, 2, nbr2);
    diffn_kernel<<<(BS * V2 * NB + 255) / 256, 256, 0, stream>>>(verts, nbr2, V2, 2, diffn2);

    // ---- half-res conv layers (c2, c3, c4, c42, c43, c44) ----
    for (int i = 6; i < 12; ++i) {
        gemm(cur, Wp(i), Bp(i), feat, BS * V2, 2 * OC[i], IC[i]);
        float* o = fmb[pb]; pb ^= 1;
        act(feat, nbr2, diffn2, Dp(i), o, V2, OC[i]);
        cur = o;
    }

    // ---- head ----
    gmax_part<<<dim3(4, 8, BS), 256, 0, stream>>>(cur, gpart);
    gmax_final<<<(BS * 1024 + 255) / 256, 256, 0, stream>>>(gpart, g);
    head_kernel<<<BS, 256, 0, stream>>>(g, fc1w, fc1b, bng, bnb, fc2w, fc2b, (float*)d_out);
}

// Round 2
// 809.115 us; speedup vs baseline: 2.4651x; 2.4651x over previous
//
#include <hip/hip_runtime.h>
#include <float.h>
#include <math.h>

#define BS 4
#define V1 2048
#define V2 1024
#define NB 20
#define KSEL 21   // k+1: take 21 nearest, drop the nearest (self)

typedef __attribute__((ext_vector_type(8))) short short8v;   // 8 x bf16 bits (4 VGPRs)
typedef __attribute__((ext_vector_type(4))) float f32x4;

__device__ __forceinline__ unsigned short f2bf(float x) {
    union { float f; unsigned u; } v; v.f = x;
    unsigned r = (v.u + 0x7fffu + ((v.u >> 16) & 1u)) >> 16;   // RNE
    return (unsigned short)r;
}
__device__ __forceinline__ float bf2f(unsigned short h) {
    return __uint_as_float((unsigned)h << 16);
}

__device__ __forceinline__ void gload16(const void* g, void* l) {
    __builtin_amdgcn_global_load_lds((const __attribute__((address_space(1))) void*)g,
                                     (__attribute__((address_space(3))) void*)l, 16, 0, 0);
}

// ---------------- kNN: one block per (b, row). dist in LDS, 21x masked argmin ----------------
__global__ __launch_bounds__(256)
void knn_kernel(const float* __restrict__ verts, int Vv, int stride, int* __restrict__ nbr)
{
    __shared__ float dist[V1];
    __shared__ unsigned long long red[4];
    __shared__ int winners[KSEL];
    int bi = blockIdx.x;
    int b = bi / Vv, i = bi % Vv;
    const float* vb = verts + (size_t)b * V1 * 3;
    int tid = threadIdx.x;
    float xi = vb[(size_t)i * stride * 3 + 0];
    float yi = vb[(size_t)i * stride * 3 + 1];
    float zi = vb[(size_t)i * stride * 3 + 2];
    float sqi = xi * xi + yi * yi + zi * zi;
    for (int j = tid; j < Vv; j += 256) {
        float xj = vb[(size_t)j * stride * 3 + 0];
        float yj = vb[(size_t)j * stride * 3 + 1];
        float zj = vb[(size_t)j * stride * 3 + 2];
        float sqj = xj * xj + yj * yj + zj * zj;
        float dt = xi * xj + yi * yj + zi * zj;
        dist[j] = sqi - 2.0f * dt + sqj;
    }
    __syncthreads();
    for (int s = 0; s < KSEL; ++s) {
        unsigned long long best = ~0ull;
        for (int j = tid; j < Vv; j += 256) {
            unsigned u = __float_as_uint(dist[j]);
            u = (u & 0x80000000u) ? ~u : (u | 0x80000000u);
            unsigned long long key = ((unsigned long long)u << 32) | (unsigned)j;
            if (key < best) best = key;
        }
        #pragma unroll
        for (int off = 32; off > 0; off >>= 1) {
            unsigned long long o = __shfl_down(best, off);
            if (o < best) best = o;
        }
        if ((tid & 63) == 0) red[tid >> 6] = best;
        __syncthreads();
        if (tid == 0) {
            unsigned long long r = red[0];
            if (red[1] < r) r = red[1];
            if (red[2] < r) r = red[2];
            if (red[3] < r) r = red[3];
            int widx = (int)(r & 0xffffffffull);
            winners[s] = widx;
            dist[widx] = FLT_MAX;
        }
        __syncthreads();
    }
    if (tid < NB) nbr[((size_t)b * Vv + i) * NB + tid] = winners[tid + 1];
}

// ---------------- normalized neighbor difference vectors ----------------
__global__ __launch_bounds__(256)
void diffn_kernel(const float* __restrict__ verts, const int* __restrict__ nbr,
                  int Vv, int stride, float* __restrict__ diffn)
{
    int t = blockIdx.x * 256 + threadIdx.x;
    int total = BS * Vv * NB;
    if (t >= total) return;
    int v = (t / NB) % Vv;
    int b = t / (NB * Vv);
    const float* vb = verts + (size_t)b * V1 * 3;
    int j = nbr[t];
    float xi = vb[(size_t)v * stride * 3 + 0];
    float yi = vb[(size_t)v * stride * 3 + 1];
    float zi = vb[(size_t)v * stride * 3 + 2];
    float dx = vb[(size_t)j * stride * 3 + 0] - xi;
    float dy = vb[(size_t)j * stride * 3 + 1] - yi;
    float dz = vb[(size_t)j * stride * 3 + 2] - zi;
    float nrm = sqrtf(dx * dx + dy * dy + dz * dz);
    float inv = 1.0f / fmaxf(nrm, 1e-12f);
    diffn[(size_t)t * 3 + 0] = dx * inv;
    diffn[(size_t)t * 3 + 1] = dy * inv;
    diffn[(size_t)t * 3 + 2] = dz * inv;
}

// ---------------- weight transpose + fp32->bf16: Wt[n][k] = bf16(W[k][n]) ----------------
__global__ __launch_bounds__(256)
void convT_kernel(const float* __restrict__ W, unsigned short* __restrict__ Wt, int K, int N)
{
    __shared__ float t[32][33];
    int k0 = blockIdx.y * 32, n0 = blockIdx.x * 32;
    int tx = threadIdx.x % 32, ty = threadIdx.x / 32;   // ty 0..7
    #pragma unroll
    for (int r = ty; r < 32; r += 8) t[r][tx] = W[(size_t)(k0 + r) * N + n0 + tx];
    __syncthreads();
    #pragma unroll
    for (int r = ty; r < 32; r += 8) Wt[(size_t)(n0 + r) * K + k0 + tx] = f2bf(t[tx][r]);
}

// ---------------- c0: feat = verts @ W(3x64) + b ----------------
__global__ __launch_bounds__(256)
void c0_kernel(const float* __restrict__ verts, const float* __restrict__ W,
               const float* __restrict__ Bv, float* __restrict__ feat)
{
    int t = blockIdx.x * 256 + threadIdx.x;
    if (t >= BS * V1 * 64) return;
    int n = t & 63, m = t >> 6;
    float x = verts[(size_t)m * 3 + 0];
    float y = verts[(size_t)m * 3 + 1];
    float z = verts[(size_t)m * 3 + 2];
    feat[t] = x * W[n] + y * W[64 + n] + z * W[128 + n] + Bv[n];
}

// ---------------- bf16 MFMA GEMM + bias: C(MxN) = A(MxK) @ Wt(NxK)^T + bias ----------------
// 128x128 tile, 4 waves (2x2), each wave 64x64 = 4x4 frags of 16x16x32.
// LDS linear rows [128][BK] bf16, XOR-swizzled via pre-swizzled global source (rule #21).
template<int BK>
__global__ __launch_bounds__(256)
void gemm_mfma(const unsigned short* __restrict__ A, const unsigned short* __restrict__ Wt,
               const float* __restrict__ bias, float* __restrict__ C,
               int M, int N, int K)
{
    constexpr int RB = BK * 2;               // row bytes
    constexpr int TILE_B = 128 * RB;         // bytes per matrix tile
    constexpr int SWM = (BK == 64) ? 7 : 3;  // swizzle row mask
    __shared__ __align__(16) char smem[2 * TILE_B];
    int tid = threadIdx.x;
    int lane = tid & 63, wid = tid >> 6;
    int wr = wid >> 1, wc = wid & 1;
    int m0 = blockIdx.y * 128, n0 = blockIdx.x * 128;

    f32x4 acc[4][4] = {};

    constexpr int rounds = TILE_B / 4096;
    int srow[rounds], soffe[rounds];
    #pragma unroll
    for (int r = 0; r < rounds; ++r) {
        int L = r * 4096 + tid * 16;
        int row = L / RB;
        int off = (L % RB) ^ ((row & SWM) << 4);
        srow[r] = row; soffe[r] = off >> 1;
    }

    for (int kt = 0; kt < K; kt += BK) {
        #pragma unroll
        for (int r = 0; r < rounds; ++r)
            gload16(A + (size_t)(m0 + srow[r]) * K + kt + soffe[r],
                    smem + r * 4096 + wid * 1024);
        #pragma unroll
        for (int r = 0; r < rounds; ++r)
            gload16(Wt + (size_t)(n0 + srow[r]) * K + kt + soffe[r],
                    smem + TILE_B + r * 4096 + wid * 1024);
        asm volatile("s_waitcnt vmcnt(0)" ::: "memory");
        __syncthreads();
        #pragma unroll
        for (int ks = 0; ks < BK / 32; ++ks) {
            short8v av[4], bv[4];
            #pragma unroll
            for (int i = 0; i < 4; ++i) {
                int row = wr * 64 + i * 16 + (lane & 15);
                int off = (ks * 64 + ((lane >> 4) * 16)) ^ ((row & SWM) << 4);
                av[i] = *(const short8v*)(smem + row * RB + off);
            }
            #pragma unroll
            for (int j = 0; j < 4; ++j) {
                int row = wc * 64 + j * 16 + (lane & 15);
                int off = (ks * 64 + ((lane >> 4) * 16)) ^ ((row & SWM) << 4);
                bv[j] = *(const short8v*)(smem + TILE_B + row * RB + off);
            }
            #pragma unroll
            for (int i = 0; i < 4; ++i)
                #pragma unroll
                for (int j = 0; j < 4; ++j)
                    acc[i][j] = __builtin_amdgcn_mfma_f32_16x16x32_bf16(av[i], bv[j], acc[i][j], 0, 0, 0);
        }
        __syncthreads();
    }
    // epilogue: C/D layout col=lane&15, row=(lane>>4)*4+reg
    #pragma unroll
    for (int i = 0; i < 4; ++i) {
        #pragma unroll
        for (int j = 0; j < 4; ++j) {
            int col = n0 + wc * 64 + j * 16 + (lane & 15);
            int rowb = m0 + wr * 64 + i * 16 + ((lane >> 4) * 4);
            float bv2 = bias[col];
            #pragma unroll
            for (int v = 0; v < 4; ++v)
                C[(size_t)(rowb + v) * N + col] = acc[i][j][v] + bv2;
        }
    }
}

// ---------------- act epilogue: out = center + max_n(theta * support); dual fp32/bf16 out ----
__global__ __launch_bounds__(256)
void act_kernel(const float* __restrict__ feat, const int* __restrict__ nbr,
                const float* __restrict__ diffn, const float* __restrict__ dmat,
                float* __restrict__ outp, unsigned short* __restrict__ outh,
                int Vv, int OC)
{
    int OC4 = OC >> 2;
    int t = blockIdx.x * 256 + threadIdx.x;
    int total = BS * Vv * OC4;
    if (t >= total) return;
    int c4 = t % OC4;
    int v = (t / OC4) % Vv;
    int b = t / (OC4 * Vv);
    const float4* d4 = (const float4*)dmat;
    float4 D0 = d4[c4], D1 = d4[OC4 + c4], D2 = d4[2 * OC4 + c4];
    float n0 = sqrtf(D0.x * D0.x + D1.x * D1.x + D2.x * D2.x);
    float n1 = sqrtf(D0.y * D0.y + D1.y * D1.y + D2.y * D2.y);
    float n2 = sqrtf(D0.z * D0.z + D1.z * D1.z + D2.z * D2.z);
    float n3 = sqrtf(D0.w * D0.w + D1.w * D1.w + D2.w * D2.w);
    float i0 = 1.0f / fmaxf(n0, 1e-12f);
    float i1 = 1.0f / fmaxf(n1, 1e-12f);
    float i2 = 1.0f / fmaxf(n2, 1e-12f);
    float i3 = 1.0f / fmaxf(n3, 1e-12f);
    D0.x *= i0; D0.y *= i1; D0.z *= i2; D0.w *= i3;
    D1.x *= i0; D1.y *= i1; D1.z *= i2; D1.w *= i3;
    D2.x *= i0; D2.y *= i1; D2.z *= i2; D2.w *= i3;

    const int* nb = nbr + ((size_t)b * Vv + v) * NB;
    const float* dfn = diffn + ((size_t)b * Vv + v) * NB * 3;
    const float4* frow = (const float4*)feat;
    size_t rowstride = (size_t)(2 * OC4);
    const float4* fsup = frow + (size_t)b * Vv * rowstride + OC4 + c4;
    float4 m = make_float4(-FLT_MAX, -FLT_MAX, -FLT_MAX, -FLT_MAX);
    for (int n = 0; n < NB; ++n) {
        int idx = nb[n];
        float e0 = dfn[3 * n + 0], e1 = dfn[3 * n + 1], e2 = dfn[3 * n + 2];
        float4 s = fsup[(size_t)idx * rowstride];
        float th;
        th = e0 * D0.x + e1 * D1.x + e2 * D2.x; m.x = fmaxf(m.x, th * s.x);
        th = e0 * D0.y + e1 * D1.y + e2 * D2.y; m.y = fmaxf(m.y, th * s.y);
        th = e0 * D0.z + e1 * D1.z + e2 * D2.z; m.z = fmaxf(m.z, th * s.z);
        th = e0 * D0.w + e1 * D1.w + e2 * D2.w; m.w = fmaxf(m.w, th * s.w);
    }
    float4 cen = frow[(size_t)b * Vv * rowstride + (size_t)v * rowstride + c4];
    float4 r = make_float4(cen.x + m.x, cen.y + m.y, cen.z + m.z, cen.w + m.w);
    size_t oidx = ((size_t)b * Vv + v) * OC4 + c4;
    ushort4 h;
    h.x = f2bf(r.x); h.y = f2bf(r.y); h.z = f2bf(r.z); h.w = f2bf(r.w);
    ((ushort4*)outh)[oidx] = h;
    if (outp) ((float4*)outp)[oidx] = r;
}

// ---------------- neighbor max-pool + stride-2 subsample (64 ch, bf16 in/out) ----------------
__global__ __launch_bounds__(256)
void pool_kernel(const ushort4* __restrict__ fmh, const int* __restrict__ nbr,
                 ushort4* __restrict__ outp)
{
    const int C4 = 16;   // 64/4
    int t = blockIdx.x * 256 + threadIdx.x;
    int total = BS * V2 * C4;
    if (t >= total) return;
    int c = t % C4;
    int v2 = (t / C4) % V2;
    int b = t / (C4 * V2);
    const int* nb = nbr + ((size_t)b * V1 + 2 * v2) * NB;
    float4 m = make_float4(-FLT_MAX, -FLT_MAX, -FLT_MAX, -FLT_MAX);
    for (int n = 0; n < NB; ++n) {
        int idx = nb[n];
        ushort4 s = fmh[((size_t)b * V1 + idx) * C4 + c];
        m.x = fmaxf(m.x, bf2f(s.x)); m.y = fmaxf(m.y, bf2f(s.y));
        m.z = fmaxf(m.z, bf2f(s.z)); m.w = fmaxf(m.w, bf2f(s.w));
    }
    ushort4 h;
    h.x = f2bf(m.x); h.y = f2bf(m.y); h.z = f2bf(m.z); h.w = f2bf(m.w);
    outp[((size_t)b * V2 + v2) * C4 + c] = h;
}

// ---------------- global max over vertices (two stage) ----------------
__global__ __launch_bounds__(256)
void gmax_part(const float* __restrict__ fm, float* __restrict__ part)
{
    int c = blockIdx.x * 256 + threadIdx.x;
    int ch = blockIdx.y;
    int b = blockIdx.z;
    float m = -FLT_MAX;
    for (int v = ch * 128; v < (ch + 1) * 128; ++v)
        m = fmaxf(m, fm[((size_t)b * V2 + v) * 1024 + c]);
    part[((size_t)b * 8 + ch) * 1024 + c] = m;
}

__global__ __launch_bounds__(256)
void gmax_final(const float* __restrict__ part, float* __restrict__ g)
{
    int t = blockIdx.x * 256 + threadIdx.x;
    if (t >= BS * 1024) return;
    int c = t % 1024, b = t / 1024;
    float m = -FLT_MAX;
    for (int ch = 0; ch < 8; ++ch)
        m = fmaxf(m, part[((size_t)b * 8 + ch) * 1024 + c]);
    g[t] = m;
}

// ---------------- head: fc1 + bn + relu + fc2 ----------------
__global__ __launch_bounds__(256)
void head_kernel(const float* __restrict__ g, const float* __restrict__ fc1w,
                 const float* __restrict__ fc1b, const float* __restrict__ bng,
                 const float* __restrict__ bnb, const float* __restrict__ fc2w,
                 const float* __restrict__ fc2b, float* __restrict__ outp)
{
    __shared__ float gs[1024];
    __shared__ float hs[256];
    int b = blockIdx.x;
    int j = threadIdx.x;
    for (int k = j; k < 1024; k += 256) gs[k] = g[(size_t)b * 1024 + k];
    __syncthreads();
    float h = fc1b[j];
    for (int k = 0; k < 1024; ++k) h = fmaf(gs[k], fc1w[(size_t)k * 256 + j], h);
    const float rc = 0.99999500003749937f;
    h = h * rc * bng[j] + bnb[j];
    h = fmaxf(h, 0.0f);
    hs[j] = h;
    __syncthreads();
    if (j < 40) {
        float o = fc2b[j];
        for (int k = 0; k < 256; ++k) o = fmaf(hs[k], fc2w[(size_t)k * 40 + j], o);
        outp[(size_t)b * 40 + j] = o;
    }
}

// ---------------- host driver ----------------
extern "C" void kernel_launch(void* const* d_in, const int* in_sizes, int n_in,
                              void* d_out, int out_size, void* d_ws, size_t ws_size,
                              hipStream_t stream)
{
    (void)in_sizes; (void)n_in; (void)out_size; (void)ws_size;
    const float* verts = (const float*)d_in[0];
    auto Wp = [&](int i) { return (const float*)d_in[1 + 3 * i]; };
    auto Bp = [&](int i) { return (const float*)d_in[2 + 3 * i]; };
    auto Dp = [&](int i) { return (const float*)d_in[3 + 3 * i]; };
    const float* fc1w = (const float*)d_in[37];
    const float* fc1b = (const float*)d_in[38];
    const float* bng  = (const float*)d_in[39];
    const float* bnb  = (const float*)d_in[40];
    const float* fc2w = (const float*)d_in[41];
    const float* fc2b = (const float*)d_in[42];

    static const int IC[12] = {3, 32, 64, 64, 64, 64, 64, 128, 256, 1024, 1024, 1024};
    static const int OC[12] = {32, 64, 64, 64, 64, 64, 128, 256, 1024, 1024, 1024, 1024};

    char* ws = (char*)d_ws;
    size_t off = 0;
    auto alloc = [&](size_t bytes) {
        void* p = ws + off;
        off += (bytes + 255) & ~(size_t)255;
        return p;
    };
    int*   nbr1   = (int*)alloc((size_t)BS * V1 * NB * 4);
    int*   nbr2   = (int*)alloc((size_t)BS * V2 * NB * 4);
    float* diffn1 = (float*)alloc((size_t)BS * V1 * NB * 3 * 4);
    float* diffn2 = (float*)alloc((size_t)BS * V2 * NB * 3 * 4);
    float* feat   = (float*)alloc((size_t)BS * V2 * 2048 * 4);           // 33.5 MB
    unsigned short* fmh0 = (unsigned short*)alloc((size_t)BS * V2 * 1024 * 2);  // 8.4 MB
    unsigned short* fmh1 = (unsigned short*)alloc((size_t)BS * V2 * 1024 * 2);  // 8.4 MB
    float* fm32   = (float*)alloc((size_t)BS * V2 * 1024 * 4);           // 16.8 MB (c44 only)
    float* gpart  = (float*)alloc((size_t)BS * 8 * 1024 * 4);
    float* g      = (float*)alloc((size_t)BS * 1024 * 4);

    // bf16 transposed weights per layer (layers 1..11)
    unsigned short* WtBuf[12];
    {
        size_t total = 0;
        for (int i = 1; i < 12; ++i) total += (size_t)(2 * OC[i]) * IC[i];
        unsigned short* base = (unsigned short*)alloc(total * 2);
        size_t o2 = 0;
        for (int i = 1; i < 12; ++i) { WtBuf[i] = base + o2; o2 += (size_t)(2 * OC[i]) * IC[i]; }
    }
    for (int i = 1; i < 12; ++i) {
        int K = IC[i], N = 2 * OC[i];
        dim3 gdim(N / 32, K / 32);
        convT_kernel<<<gdim, 256, 0, stream>>>(Wp(i), WtBuf[i], K, N);
    }

    auto gemm = [&](const unsigned short* A, int li, float* Cc, int M) {
        int K = IC[li], N = 2 * OC[li];
        dim3 gdim(N / 128, M / 128);
        if (K % 64 == 0)
            gemm_mfma<64><<<gdim, 256, 0, stream>>>(A, WtBuf[li], Bp(li), Cc, M, N, K);
        else
            gemm_mfma<32><<<gdim, 256, 0, stream>>>(A, WtBuf[li], Bp(li), Cc, M, N, K);
    };
    auto act = [&](const float* f, const int* nbr, const float* dfn, const float* d,
                   float* outp, unsigned short* outh, int Vv, int oc) {
        int total = BS * Vv * (oc / 4);
        act_kernel<<<(total + 255) / 256, 256, 0, stream>>>(f, nbr, dfn, d, outp, outh, Vv, oc);
    };

    // ---- stage 1: full-res kNN + diffs ----
    knn_kernel<<<BS * V1, 256, 0, stream>>>(verts, V1, 1, nbr1);
    diffn_kernel<<<(BS * V1 * NB + 255) / 256, 256, 0, stream>>>(verts, nbr1, V1, 1, diffn1);

    // ---- c0 (fp32 tiny GEMM) + act ----
    c0_kernel<<<(BS * V1 * 64 + 255) / 256, 256, 0, stream>>>(verts, Wp(0), Bp(0), feat);
    unsigned short* hb[2] = {fmh0, fmh1};
    int pb = 0;
    act(feat, nbr1, diffn1, Dp(0), nullptr, hb[pb], V1, OC[0]);
    const unsigned short* cur = hb[pb]; pb ^= 1;

    // ---- full-res conv layers (c1, c12, c13, c14, p1) ----
    for (int i = 1; i < 6; ++i) {
        gemm(cur, i, feat, BS * V1);
        act(feat, nbr1, diffn1, Dp(i), nullptr, hb[pb], V1, OC[i]);
        cur = hb[pb]; pb ^= 1;
    }

    // ---- pool (neighbor max at full res, subsample stride 2, bf16) ----
    {
        int total = BS * V2 * 16;
        pool_kernel<<<(total + 255) / 256, 256, 0, stream>>>(
            (const ushort4*)cur, nbr1, (ushort4*)hb[pb]);
        cur = hb[pb]; pb ^= 1;
    }

    // ---- stage 2: half-res kNN + diffs ----
    knn_kernel<<<BS * V2, 256, 0, stream>>>(verts, V2, 2, nbr2);
    diffn_kernel<<<(BS * V2 * NB + 255) / 256, 256, 0, stream>>>(verts, nbr2, V2, 2, diffn2);

    // ---- half-res conv layers (c2, c3, c4, c42, c43, c44) ----
    for (int i = 6; i < 12; ++i) {
        gemm(cur, i, feat, BS * V2);
        float* f32out = (i == 11) ? fm32 : nullptr;
        act(feat, nbr2, diffn2, Dp(i), f32out, hb[pb], V2, OC[i]);
        cur = hb[pb]; pb ^= 1;
    }

    // ---- head ----
    gmax_part<<<dim3(4, 8, BS), 256, 0, stream>>>(fm32, gpart);
    gmax_final<<<(BS * 1024 + 255) / 256, 256, 0, stream>>>(gpart, g);
    head_kernel<<<BS, 256, 0, stream>>>(g, fc1w, fc1b, bng, bnb, fc2w, fc2b, (float*)d_out);
}

// Round 4
// 675.635 us; speedup vs baseline: 2.9521x; 1.1976x over previous
//
#include <hip/hip_runtime.h>
#include <float.h>
#include <math.h>

#define BS 4
#define V1 2048
#define V2 1024
#define NB 20
#define KSEL 21   // k+1: take 21 nearest, drop the nearest (self)

typedef __attribute__((ext_vector_type(8))) short short8v;   // 8 x bf16 bits (4 VGPRs)
typedef __attribute__((ext_vector_type(4))) float f32x4;

__device__ __forceinline__ unsigned short f2bf(float x) {
    union { float f; unsigned u; } v; v.f = x;
    unsigned r = (v.u + 0x7fffu + ((v.u >> 16) & 1u)) >> 16;   // RNE
    return (unsigned short)r;
}
__device__ __forceinline__ float bf2f(unsigned short h) {
    return __uint_as_float((unsigned)h << 16);
}
__device__ __forceinline__ unsigned umin32(unsigned a, unsigned b) { return a < b ? a : b; }

__device__ __forceinline__ void gload16(const void* g, void* l) {
    __builtin_amdgcn_global_load_lds((const __attribute__((address_space(1))) void*)g,
                                     (__attribute__((address_space(3))) void*)l, 16, 0, 0);
}

// ---------------- kNN: one WAVE per query. keys in registers, no barriers in loop ----------
// key = (monotonic_dist & ~31) | slot ; candidate j = slot*64 + lane
template<int SLOTS>
__global__ __launch_bounds__(256)
void knn_wave_kernel(const float* __restrict__ verts, int stride, int* __restrict__ nbr)
{
    constexpr int Vv = SLOTS * 64;
    __shared__ float xs[Vv], ys[Vv], zs[Vv];
    int tid = threadIdx.x;
    int lane = tid & 63;
    int wv = tid >> 6;                    // wave id 0..3
    int b = blockIdx.x / (Vv / 4);
    int q0 = (blockIdx.x % (Vv / 4)) * 4;
    const float* vb = verts + (size_t)b * V1 * 3;
    for (int p = tid; p < Vv; p += 256) {
        xs[p] = vb[(size_t)p * stride * 3 + 0];
        ys[p] = vb[(size_t)p * stride * 3 + 1];
        zs[p] = vb[(size_t)p * stride * 3 + 2];
    }
    __syncthreads();
    int i = q0 + wv;                      // this wave's query
    float xi = xs[i], yi = ys[i], zi = zs[i];
    float sqi = xi * xi + yi * yi + zi * zi;
    unsigned keys[SLOTS];
    #pragma unroll
    for (int s = 0; s < SLOTS; ++s) {
        int j = s * 64 + lane;
        float xj = xs[j], yj = ys[j], zj = zs[j];
        float sqj = xj * xj + yj * yj + zj * zj;
        float d = sqi - 2.0f * (xi * xj + yi * yj + zi * zj) + sqj;
        unsigned u = __float_as_uint(d);
        u = (u & 0x80000000u) ? ~u : (u | 0x80000000u);
        keys[s] = (u & ~31u) | (unsigned)s;
    }
    unsigned lm = keys[0];
    #pragma unroll
    for (int s = 1; s < SLOTS; ++s) lm = umin32(lm, keys[s]);

    int* out = nbr + ((size_t)b * Vv + i) * NB;
    for (int it = 0; it < KSEL; ++it) {
        unsigned m = lm;
        #pragma unroll
        for (int off = 1; off < 64; off <<= 1)
            m = umin32(m, (unsigned)__shfl_xor((int)m, off));
        unsigned long long bal = __ballot(lm == m);
        int wl = __ffsll(bal) - 1;
        int slot = (int)(m & 31u);
        int j = slot * 64 + wl;
        if (it > 0 && lane == 0) out[it - 1] = j;
        if (lane == wl) {
            #pragma unroll
            for (int s = 0; s < SLOTS; ++s)
                if (s == slot) keys[s] = 0xFFFFFFFFu;
            lm = keys[0];
            #pragma unroll
            for (int s = 1; s < SLOTS; ++s) lm = umin32(lm, keys[s]);
        }
    }
}

// ---------------- normalized neighbor difference vectors ----------------
__global__ __launch_bounds__(256)
void diffn_kernel(const float* __restrict__ verts, const int* __restrict__ nbr,
                  int Vv, int stride, float* __restrict__ diffn)
{
    int t = blockIdx.x * 256 + threadIdx.x;
    int total = BS * Vv * NB;
    if (t >= total) return;
    int v = (t / NB) % Vv;
    int b = t / (NB * Vv);
    const float* vb = verts + (size_t)b * V1 * 3;
    int j = nbr[t];
    float xi = vb[(size_t)v * stride * 3 + 0];
    float yi = vb[(size_t)v * stride * 3 + 1];
    float zi = vb[(size_t)v * stride * 3 + 2];
    float dx = vb[(size_t)j * stride * 3 + 0] - xi;
    float dy = vb[(size_t)j * stride * 3 + 1] - yi;
    float dz = vb[(size_t)j * stride * 3 + 2] - zi;
    float nrm = sqrtf(dx * dx + dy * dy + dz * dz);
    float inv = 1.0f / fmaxf(nrm, 1e-12f);
    diffn[(size_t)t * 3 + 0] = dx * inv;
    diffn[(size_t)t * 3 + 1] = dy * inv;
    diffn[(size_t)t * 3 + 2] = dz * inv;
}

// ---------------- weight transpose + fp32->bf16: Wt[n][k] = bf16(W[k][n]) ----------------
__global__ __launch_bounds__(256)
void convT_kernel(const float* __restrict__ W, unsigned short* __restrict__ Wt, int K, int N)
{
    __shared__ float t[32][33];
    int k0 = blockIdx.y * 32, n0 = blockIdx.x * 32;
    int tx = threadIdx.x % 32, ty = threadIdx.x / 32;   // ty 0..7
    #pragma unroll
    for (int r = ty; r < 32; r += 8) t[r][tx] = W[(size_t)(k0 + r) * N + n0 + tx];
    __syncthreads();
    #pragma unroll
    for (int r = ty; r < 32; r += 8) Wt[(size_t)(n0 + r) * K + k0 + tx] = f2bf(t[tx][r]);
}

// ---------------- c0: feat = verts @ W(3x64) + b ----------------
__global__ __launch_bounds__(256)
void c0_kernel(const float* __restrict__ verts, const float* __restrict__ W,
               const float* __restrict__ Bv, float* __restrict__ feat)
{
    int t = blockIdx.x * 256 + threadIdx.x;
    if (t >= BS * V1 * 64) return;
    int n = t & 63, m = t >> 6;
    float x = verts[(size_t)m * 3 + 0];
    float y = verts[(size_t)m * 3 + 1];
    float z = verts[(size_t)m * 3 + 2];
    feat[t] = x * W[n] + y * W[64 + n] + z * W[128 + n] + Bv[n];
}

// ---------------- bf16 MFMA GEMM + bias: C(MxN) = A(MxK) @ Wt(NxK)^T + bias ----------------
template<int BK>
__global__ __launch_bounds__(256)
void gemm_mfma(const unsigned short* __restrict__ A, const unsigned short* __restrict__ Wt,
               const float* __restrict__ bias, float* __restrict__ C,
               int M, int N, int K)
{
    constexpr int RB = BK * 2;               // row bytes
    constexpr int TILE_B = 128 * RB;         // bytes per matrix tile
    constexpr int SWM = (BK == 64) ? 7 : 3;  // swizzle row mask
    __shared__ __align__(16) char smem[2 * TILE_B];
    int tid = threadIdx.x;
    int lane = tid & 63, wid = tid >> 6;
    int wr = wid >> 1, wc = wid & 1;
    int m0 = blockIdx.y * 128, n0 = blockIdx.x * 128;

    f32x4 acc[4][4] = {};

    constexpr int rounds = TILE_B / 4096;
    int srow[rounds], soffe[rounds];
    #pragma unroll
    for (int r = 0; r < rounds; ++r) {
        int L = r * 4096 + tid * 16;
        int row = L / RB;
        int off = (L % RB) ^ ((row & SWM) << 4);
        srow[r] = row; soffe[r] = off >> 1;
    }

    for (int kt = 0; kt < K; kt += BK) {
        #pragma unroll
        for (int r = 0; r < rounds; ++r)
            gload16(A + (size_t)(m0 + srow[r]) * K + kt + soffe[r],
                    smem + r * 4096 + wid * 1024);
        #pragma unroll
        for (int r = 0; r < rounds; ++r)
            gload16(Wt + (size_t)(n0 + srow[r]) * K + kt + soffe[r],
                    smem + TILE_B + r * 4096 + wid * 1024);
        asm volatile("s_waitcnt vmcnt(0)" ::: "memory");
        __syncthreads();
        #pragma unroll
        for (int ks = 0; ks < BK / 32; ++ks) {
            short8v av[4], bv[4];
            #pragma unroll
            for (int i = 0; i < 4; ++i) {
                int row = wr * 64 + i * 16 + (lane & 15);
                int off = (ks * 64 + ((lane >> 4) * 16)) ^ ((row & SWM) << 4);
                av[i] = *(const short8v*)(smem + row * RB + off);
            }
            #pragma unroll
            for (int j = 0; j < 4; ++j) {
                int row = wc * 64 + j * 16 + (lane & 15);
                int off = (ks * 64 + ((lane >> 4) * 16)) ^ ((row & SWM) << 4);
                bv[j] = *(const short8v*)(smem + TILE_B + row * RB + off);
            }
            #pragma unroll
            for (int i = 0; i < 4; ++i)
                #pragma unroll
                for (int j = 0; j < 4; ++j)
                    acc[i][j] = __builtin_amdgcn_mfma_f32_16x16x32_bf16(av[i], bv[j], acc[i][j], 0, 0, 0);
        }
        __syncthreads();
    }
    #pragma unroll
    for (int i = 0; i < 4; ++i) {
        #pragma unroll
        for (int j = 0; j < 4; ++j) {
            int col = n0 + wc * 64 + j * 16 + (lane & 15);
            int rowb = m0 + wr * 64 + i * 16 + ((lane >> 4) * 4);
            float bv2 = bias[col];
            #pragma unroll
            for (int v = 0; v < 4; ++v)
                C[(size_t)(rowb + v) * N + col] = acc[i][j][v] + bv2;
        }
    }
}

// ---------------- act epilogue: out = center + max_n(theta * support); dual fp32/bf16 out ----
__global__ __launch_bounds__(256)
void act_kernel(const float* __restrict__ feat, const int* __restrict__ nbr,
                const float* __restrict__ diffn, const float* __restrict__ dmat,
                float* __restrict__ outp, unsigned short* __restrict__ outh,
                int Vv, int OC)
{
    int OC4 = OC >> 2;
    int t = blockIdx.x * 256 + threadIdx.x;
    int total = BS * Vv * OC4;
    if (t >= total) return;
    int c4 = t % OC4;
    int v = (t / OC4) % Vv;
    int b = t / (OC4 * Vv);
    const float4* d4 = (const float4*)dmat;
    float4 D0 = d4[c4], D1 = d4[OC4 + c4], D2 = d4[2 * OC4 + c4];
    float n0 = sqrtf(D0.x * D0.x + D1.x * D1.x + D2.x * D2.x);
    float n1 = sqrtf(D0.y * D0.y + D1.y * D1.y + D2.y * D2.y);
    float n2 = sqrtf(D0.z * D0.z + D1.z * D1.z + D2.z * D2.z);
    float n3 = sqrtf(D0.w * D0.w + D1.w * D1.w + D2.w * D2.w);
    float i0 = 1.0f / fmaxf(n0, 1e-12f);
    float i1 = 1.0f / fmaxf(n1, 1e-12f);
    float i2 = 1.0f / fmaxf(n2, 1e-12f);
    float i3 = 1.0f / fmaxf(n3, 1e-12f);
    D0.x *= i0; D0.y *= i1; D0.z *= i2; D0.w *= i3;
    D1.x *= i0; D1.y *= i1; D1.z *= i2; D1.w *= i3;
    D2.x *= i0; D2.y *= i1; D2.z *= i2; D2.w *= i3;

    const int* nb = nbr + ((size_t)b * Vv + v) * NB;
    const float* dfn = diffn + ((size_t)b * Vv + v) * NB * 3;
    const float4* frow = (const float4*)feat;
    size_t rowstride = (size_t)(2 * OC4);
    const float4* fsup = frow + (size_t)b * Vv * rowstride + OC4 + c4;
    float4 m = make_float4(-FLT_MAX, -FLT_MAX, -FLT_MAX, -FLT_MAX);
    for (int n = 0; n < NB; ++n) {
        int idx = nb[n];
        float e0 = dfn[3 * n + 0], e1 = dfn[3 * n + 1], e2 = dfn[3 * n + 2];
        float4 s = fsup[(size_t)idx * rowstride];
        float th;
        th = e0 * D0.x + e1 * D1.x + e2 * D2.x; m.x = fmaxf(m.x, th * s.x);
        th = e0 * D0.y + e1 * D1.y + e2 * D2.y; m.y = fmaxf(m.y, th * s.y);
        th = e0 * D0.z + e1 * D1.z + e2 * D2.z; m.z = fmaxf(m.z, th * s.z);
        th = e0 * D0.w + e1 * D1.w + e2 * D2.w; m.w = fmaxf(m.w, th * s.w);
    }
    float4 cen = frow[(size_t)b * Vv * rowstride + (size_t)v * rowstride + c4];
    float4 r = make_float4(cen.x + m.x, cen.y + m.y, cen.z + m.z, cen.w + m.w);
    size_t oidx = ((size_t)b * Vv + v) * OC4 + c4;
    ushort4 h;
    h.x = f2bf(r.x); h.y = f2bf(r.y); h.z = f2bf(r.z); h.w = f2bf(r.w);
    ((ushort4*)outh)[oidx] = h;
    if (outp) ((float4*)outp)[oidx] = r;
}

// ---------------- neighbor max-pool + stride-2 subsample (64 ch, bf16 in/out) ----------------
__global__ __launch_bounds__(256)
void pool_kernel(const ushort4* __restrict__ fmh, const int* __restrict__ nbr,
                 ushort4* __restrict__ outp)
{
    const int C4 = 16;   // 64/4
    int t = blockIdx.x * 256 + threadIdx.x;
    int total = BS * V2 * C4;
    if (t >= total) return;
    int c = t % C4;
    int v2 = (t / C4) % V2;
    int b = t / (C4 * V2);
    const int* nb = nbr + ((size_t)b * V1 + 2 * v2) * NB;
    float4 m = make_float4(-FLT_MAX, -FLT_MAX, -FLT_MAX, -FLT_MAX);
    for (int n = 0; n < NB; ++n) {
        int idx = nb[n];
        ushort4 s = fmh[((size_t)b * V1 + idx) * C4 + c];
        m.x = fmaxf(m.x, bf2f(s.x)); m.y = fmaxf(m.y, bf2f(s.y));
        m.z = fmaxf(m.z, bf2f(s.z)); m.w = fmaxf(m.w, bf2f(s.w));
    }
    ushort4 h;
    h.x = f2bf(m.x); h.y = f2bf(m.y); h.z = f2bf(m.z); h.w = f2bf(m.w);
    outp[((size_t)b * V2 + v2) * C4 + c] = h;
}

// ---------------- global max over vertices (two stage) ----------------
__global__ __launch_bounds__(256)
void gmax_part(const float* __restrict__ fm, float* __restrict__ part)
{
    int c = blockIdx.x * 256 + threadIdx.x;
    int ch = blockIdx.y;
    int b = blockIdx.z;
    float m = -FLT_MAX;
    for (int v = ch * 128; v < (ch + 1) * 128; ++v)
        m = fmaxf(m, fm[((size_t)b * V2 + v) * 1024 + c]);
    part[((size_t)b * 8 + ch) * 1024 + c] = m;
}

__global__ __launch_bounds__(256)
void gmax_final(const float* __restrict__ part, float* __restrict__ g)
{
    int t = blockIdx.x * 256 + threadIdx.x;
    if (t >= BS * 1024) return;
    int c = t % 1024, b = t / 1024;
    float m = -FLT_MAX;
    for (int ch = 0; ch < 8; ++ch)
        m = fmaxf(m, part[((size_t)b * 8 + ch) * 1024 + c]);
    g[t] = m;
}

// ---------------- head: fc1 + bn + relu + fc2 ----------------
__global__ __launch_bounds__(256)
void head_kernel(const float* __restrict__ g, const float* __restrict__ fc1w,
                 const float* __restrict__ fc1b, const float* __restrict__ bng,
                 const float* __restrict__ bnb, const float* __restrict__ fc2w,
                 const float* __restrict__ fc2b, float* __restrict__ outp)
{
    __shared__ float gs[1024];
    __shared__ float hs[256];
    int b = blockIdx.x;
    int j = threadIdx.x;
    for (int k = j; k < 1024; k += 256) gs[k] = g[(size_t)b * 1024 + k];
    __syncthreads();
    float h = fc1b[j];
    for (int k = 0; k < 1024; ++k) h = fmaf(gs[k], fc1w[(size_t)k * 256 + j], h);
    const float rc = 0.99999500003749937f;
    h = h * rc * bng[j] + bnb[j];
    h = fmaxf(h, 0.0f);
    hs[j] = h;
    __syncthreads();
    if (j < 40) {
        float o = fc2b[j];
        for (int k = 0; k < 256; ++k) o = fmaf(hs[k], fc2w[(size_t)k * 40 + j], o);
        outp[(size_t)b * 40 + j] = o;
    }
}

// ---------------- host driver ----------------
extern "C" void kernel_launch(void* const* d_in, const int* in_sizes, int n_in,
                              void* d_out, int out_size, void* d_ws, size_t ws_size,
                              hipStream_t stream)
{
    (void)in_sizes; (void)n_in; (void)out_size; (void)ws_size;
    const float* verts = (const float*)d_in[0];
    auto Wp = [&](int i) { return (const float*)d_in[1 + 3 * i]; };
    auto Bp = [&](int i) { return (const float*)d_in[2 + 3 * i]; };
    auto Dp = [&](int i) { return (const float*)d_in[3 + 3 * i]; };
    const float* fc1w = (const float*)d_in[37];
    const float* fc1b = (const float*)d_in[38];
    const float* bng  = (const float*)d_in[39];
    const float* bnb  = (const float*)d_in[40];
    const float* fc2w = (const float*)d_in[41];
    const float* fc2b = (const float*)d_in[42];

    static const int IC[12] = {3, 32, 64, 64, 64, 64, 64, 128, 256, 1024, 1024, 1024};
    static const int OC[12] = {32, 64, 64, 64, 64, 64, 128, 256, 1024, 1024, 1024, 1024};

    char* ws = (char*)d_ws;
    size_t off = 0;
    auto alloc = [&](size_t bytes) {
        void* p = ws + off;
        off += (bytes + 255) & ~(size_t)255;
        return p;
    };
    int*   nbr1   = (int*)alloc((size_t)BS * V1 * NB * 4);
    int*   nbr2   = (int*)alloc((size_t)BS * V2 * NB * 4);
    float* diffn1 = (float*)alloc((size_t)BS * V1 * NB * 3 * 4);
    float* diffn2 = (float*)alloc((size_t)BS * V2 * NB * 3 * 4);
    float* feat   = (float*)alloc((size_t)BS * V2 * 2048 * 4);           // 33.5 MB
    unsigned short* fmh0 = (unsigned short*)alloc((size_t)BS * V2 * 1024 * 2);  // 8.4 MB
    unsigned short* fmh1 = (unsigned short*)alloc((size_t)BS * V2 * 1024 * 2);  // 8.4 MB
    float* fm32   = (float*)alloc((size_t)BS * V2 * 1024 * 4);           // 16.8 MB (c44 only)
    float* gpart  = (float*)alloc((size_t)BS * 8 * 1024 * 4);
    float* g      = (float*)alloc((size_t)BS * 1024 * 4);

    // bf16 transposed weights per layer (layers 1..11)
    unsigned short* WtBuf[12];
    {
        size_t total = 0;
        for (int i = 1; i < 12; ++i) total += (size_t)(2 * OC[i]) * IC[i];
        unsigned short* base = (unsigned short*)alloc(total * 2);
        size_t o2 = 0;
        for (int i = 1; i < 12; ++i) { WtBuf[i] = base + o2; o2 += (size_t)(2 * OC[i]) * IC[i]; }
    }
    for (int i = 1; i < 12; ++i) {
        int K = IC[i], N = 2 * OC[i];
        dim3 gdim(N / 32, K / 32);
        convT_kernel<<<gdim, 256, 0, stream>>>(Wp(i), WtBuf[i], K, N);
    }

    auto gemm = [&](const unsigned short* A, int li, float* Cc, int M) {
        int K = IC[li], N = 2 * OC[li];
        dim3 gdim(N / 128, M / 128);
        if (K % 64 == 0)
            gemm_mfma<64><<<gdim, 256, 0, stream>>>(A, WtBuf[li], Bp(li), Cc, M, N, K);
        else
            gemm_mfma<32><<<gdim, 256, 0, stream>>>(A, WtBuf[li], Bp(li), Cc, M, N, K);
    };
    auto act = [&](const float* f, const int* nbr, const float* dfn, const float* d,
                   float* outp, unsigned short* outh, int Vv, int oc) {
        int total = BS * Vv * (oc / 4);
        act_kernel<<<(total + 255) / 256, 256, 0, stream>>>(f, nbr, dfn, d, outp, outh, Vv, oc);
    };

    // ---- stage 1: full-res kNN + diffs ----
    knn_wave_kernel<32><<<BS * V1 / 4, 256, 0, stream>>>(verts, 1, nbr1);
    diffn_kernel<<<(BS * V1 * NB + 255) / 256, 256, 0, stream>>>(verts, nbr1, V1, 1, diffn1);

    // ---- c0 (fp32 tiny GEMM) + act ----
    c0_kernel<<<(BS * V1 * 64 + 255) / 256, 256, 0, stream>>>(verts, Wp(0), Bp(0), feat);
    unsigned short* hb[2] = {fmh0, fmh1};
    int pb = 0;
    act(feat, nbr1, diffn1, Dp(0), nullptr, hb[pb], V1, OC[0]);
    const unsigned short* cur = hb[pb]; pb ^= 1;

    // ---- full-res conv layers (c1, c12, c13, c14, p1) ----
    for (int i = 1; i < 6; ++i) {
        gemm(cur, i, feat, BS * V1);
        act(feat, nbr1, diffn1, Dp(i), nullptr, hb[pb], V1, OC[i]);
        cur = hb[pb]; pb ^= 1;
    }

    // ---- pool (neighbor max at full res, subsample stride 2, bf16) ----
    {
        int total = BS * V2 * 16;
        pool_kernel<<<(total + 255) / 256, 256, 0, stream>>>(
            (const ushort4*)cur, nbr1, (ushort4*)hb[pb]);
        cur = hb[pb]; pb ^= 1;
    }

    // ---- stage 2: half-res kNN + diffs ----
    knn_wave_kernel<16><<<BS * V2 / 4, 256, 0, stream>>>(verts, 2, nbr2);
    diffn_kernel<<<(BS * V2 * NB + 255) / 256, 256, 0, stream>>>(verts, nbr2, V2, 2, diffn2);

    // ---- half-res conv layers (c2, c3, c4, c42, c43, c44) ----
    for (int i = 6; i < 12; ++i) {
        gemm(cur, i, feat, BS * V2);
        float* f32out = (i == 11) ? fm32 : nullptr;
        act(feat, nbr2, diffn2, Dp(i), f32out, hb[pb], V2, OC[i]);
        cur = hb[pb]; pb ^= 1;
    }

    // ---- head ----
    gmax_part<<<dim3(4, 8, BS), 256, 0, stream>>>(fm32, gpart);
    gmax_final<<<(BS * 1024 + 255) / 256, 256, 0, stream>>>(gpart, g);
    head_kernel<<<BS, 256, 0, stream>>>(g, fc1w, fc1b, bng, bnb, fc2w, fc2b, (float*)d_out);
}

// Round 6
// 603.797 us; speedup vs baseline: 3.3033x; 1.1190x over previous
//
#include <hip/hip_runtime.h>
#include <float.h>
#include <math.h>

#define BS 4
#define V1 2048
#define V2 1024
#define NB 20
#define KSEL 21   // k+1: take 21 nearest, drop the nearest (self)

typedef __attribute__((ext_vector_type(8))) short short8v;   // 8 x bf16 bits (4 VGPRs)
typedef __attribute__((ext_vector_type(4))) float f32x4;

__device__ __forceinline__ unsigned short f2bf(float x) {
    union { float f; unsigned u; } v; v.f = x;
    unsigned r = (v.u + 0x7fffu + ((v.u >> 16) & 1u)) >> 16;   // RNE
    return (unsigned short)r;
}
__device__ __forceinline__ float bf2f(unsigned short h) {
    return __uint_as_float((unsigned)h << 16);
}
__device__ __forceinline__ unsigned umin32(unsigned a, unsigned b) { return a < b ? a : b; }

__device__ __forceinline__ void gload16(const void* g, void* l) {
    __builtin_amdgcn_global_load_lds((const __attribute__((address_space(1))) void*)g,
                                     (__attribute__((address_space(3))) void*)l, 16, 0, 0);
}

// ---------------- kNN: one WAVE per query; per-lane sorted top-4 cache ----------------
// key = (monotonic_dist & ~31) | slot ; candidate j = slot*64 + lane
template<int SLOTS>
__global__ __launch_bounds__(256)
void knn_wave_kernel(const float* __restrict__ verts, int stride, int* __restrict__ nbr)
{
    constexpr int Vv = SLOTS * 64;
    __shared__ float xs[Vv], ys[Vv], zs[Vv];
    int tid = threadIdx.x;
    int lane = tid & 63;
    int wv = tid >> 6;                    // wave id 0..3
    int b = blockIdx.x / (Vv / 4);
    int q0 = (blockIdx.x % (Vv / 4)) * 4;
    const float* vb = verts + (size_t)b * V1 * 3;
    for (int p = tid; p < Vv; p += 256) {
        xs[p] = vb[(size_t)p * stride * 3 + 0];
        ys[p] = vb[(size_t)p * stride * 3 + 1];
        zs[p] = vb[(size_t)p * stride * 3 + 2];
    }
    __syncthreads();
    int i = q0 + wv;                      // this wave's query
    float xi = xs[i], yi = ys[i], zi = zs[i];
    float sqi = xi * xi + yi * yi + zi * zi;
    unsigned keys[SLOTS];
    #pragma unroll
    for (int s = 0; s < SLOTS; ++s) {
        int j = s * 64 + lane;
        float xj = xs[j], yj = ys[j], zj = zs[j];
        float sqj = xj * xj + yj * yj + zj * zj;
        float d = sqi - 2.0f * (xi * xj + yi * yj + zi * zj) + sqj;
        unsigned u = __float_as_uint(d);
        u = (u & 0x80000000u) ? ~u : (u | 0x80000000u);
        keys[s] = (u & ~31u) | (unsigned)s;
    }
    // per-lane sorted top-4 cache (keys within a lane are unique: slot in low bits)
    const unsigned UMAX = 0xFFFFFFFFu;
    unsigned c0 = UMAX, c1 = UMAX, c2 = UMAX, c3 = UMAX;
    #pragma unroll
    for (int s = 0; s < SLOTS; ++s) c0 = umin32(c0, keys[s]);
    #pragma unroll
    for (int s = 0; s < SLOTS; ++s) { unsigned k = keys[s]; if (k > c0) c1 = umin32(c1, k); }
    #pragma unroll
    for (int s = 0; s < SLOTS; ++s) { unsigned k = keys[s]; if (k > c1) c2 = umin32(c2, k); }
    #pragma unroll
    for (int s = 0; s < SLOTS; ++s) { unsigned k = keys[s]; if (k > c2) c3 = umin32(c3, k); }

    unsigned lm = c0;
    int* out = nbr + ((size_t)b * Vv + i) * NB;
    for (int it = 0; it < KSEL; ++it) {
        unsigned m = lm;
        #pragma unroll
        for (int off = 1; off < 64; off <<= 1)
            m = umin32(m, (unsigned)__shfl_xor((int)m, off));
        unsigned long long bal = __ballot(lm == m);
        int wl = __ffsll(bal) - 1;
        int slot = (int)(m & 31u);
        int j = slot * 64 + wl;
        if (it > 0 && lane == 0) out[it - 1] = j;
        if (lane == wl) {
            c0 = c1; c1 = c2; c2 = c3; c3 = UMAX;    // pop head
            if (c0 == UMAX) {                         // rare refill
                #pragma unroll
                for (int s = 0; s < SLOTS; ++s) {
                    unsigned k = keys[s];
                    if (k > m) c0 = umin32(c0, k);
                }
            }
            lm = c0;
        }
    }
}

// ---------------- normalized neighbor difference vectors ----------------
__global__ __launch_bounds__(256)
void diffn_kernel(const float* __restrict__ verts, const int* __restrict__ nbr,
                  int Vv, int stride, float* __restrict__ diffn)
{
    int t = blockIdx.x * 256 + threadIdx.x;
    int total = BS * Vv * NB;
    if (t >= total) return;
    int v = (t / NB) % Vv;
    int b = t / (NB * Vv);
    const float* vb = verts + (size_t)b * V1 * 3;
    int j = nbr[t];
    float xi = vb[(size_t)v * stride * 3 + 0];
    float yi = vb[(size_t)v * stride * 3 + 1];
    float zi = vb[(size_t)v * stride * 3 + 2];
    float dx = vb[(size_t)j * stride * 3 + 0] - xi;
    float dy = vb[(size_t)j * stride * 3 + 1] - yi;
    float dz = vb[(size_t)j * stride * 3 + 2] - zi;
    float nrm = sqrtf(dx * dx + dy * dy + dz * dz);
    float inv = 1.0f / fmaxf(nrm, 1e-12f);
    diffn[(size_t)t * 3 + 0] = dx * inv;
    diffn[(size_t)t * 3 + 1] = dy * inv;
    diffn[(size_t)t * 3 + 2] = dz * inv;
}

// ---------------- weight transpose + fp32->bf16: Wt[n][k] = bf16(W[k][n]) ----------------
__global__ __launch_bounds__(256)
void convT_kernel(const float* __restrict__ W, unsigned short* __restrict__ Wt, int K, int N)
{
    __shared__ float t[32][33];
    int k0 = blockIdx.y * 32, n0 = blockIdx.x * 32;
    int tx = threadIdx.x % 32, ty = threadIdx.x / 32;   // ty 0..7
    #pragma unroll
    for (int r = ty; r < 32; r += 8) t[r][tx] = W[(size_t)(k0 + r) * N + n0 + tx];
    __syncthreads();
    #pragma unroll
    for (int r = ty; r < 32; r += 8) Wt[(size_t)(n0 + r) * K + k0 + tx] = f2bf(t[tx][r]);
}

// ---------------- c0: feat = verts @ W(3x64) + b (bf16 out) ----------------
__global__ __launch_bounds__(256)
void c0_kernel(const float* __restrict__ verts, const float* __restrict__ W,
               const float* __restrict__ Bv, unsigned short* __restrict__ feat)
{
    int t = blockIdx.x * 256 + threadIdx.x;
    if (t >= BS * V1 * 64) return;
    int n = t & 63, m = t >> 6;
    float x = verts[(size_t)m * 3 + 0];
    float y = verts[(size_t)m * 3 + 1];
    float z = verts[(size_t)m * 3 + 2];
    feat[t] = f2bf(x * W[n] + y * W[64 + n] + z * W[128 + n] + Bv[n]);
}

// ---------------- bf16 MFMA GEMM + bias: C(MxN bf16) = A(MxK) @ Wt(NxK)^T + bias --------
template<int BK>
__global__ __launch_bounds__(256)
void gemm_mfma(const unsigned short* __restrict__ A, const unsigned short* __restrict__ Wt,
               const float* __restrict__ bias, unsigned short* __restrict__ C,
               int M, int N, int K)
{
    constexpr int RB = BK * 2;               // row bytes
    constexpr int TILE_B = 128 * RB;         // bytes per matrix tile
    constexpr int SWM = (BK == 64) ? 7 : 3;  // swizzle row mask
    __shared__ __align__(16) char smem[2 * TILE_B];
    int tid = threadIdx.x;
    int lane = tid & 63, wid = tid >> 6;
    int wr = wid >> 1, wc = wid & 1;
    int m0 = blockIdx.y * 128, n0 = blockIdx.x * 128;

    f32x4 acc[4][4] = {};

    constexpr int rounds = TILE_B / 4096;
    int srow[rounds], soffe[rounds];
    #pragma unroll
    for (int r = 0; r < rounds; ++r) {
        int L = r * 4096 + tid * 16;
        int row = L / RB;
        int off = (L % RB) ^ ((row & SWM) << 4);
        srow[r] = row; soffe[r] = off >> 1;
    }

    for (int kt = 0; kt < K; kt += BK) {
        #pragma unroll
        for (int r = 0; r < rounds; ++r)
            gload16(A + (size_t)(m0 + srow[r]) * K + kt + soffe[r],
                    smem + r * 4096 + wid * 1024);
        #pragma unroll
        for (int r = 0; r < rounds; ++r)
            gload16(Wt + (size_t)(n0 + srow[r]) * K + kt + soffe[r],
                    smem + TILE_B + r * 4096 + wid * 1024);
        asm volatile("s_waitcnt vmcnt(0)" ::: "memory");
        __syncthreads();
        #pragma unroll
        for (int ks = 0; ks < BK / 32; ++ks) {
            short8v av[4], bv[4];
            #pragma unroll
            for (int i = 0; i < 4; ++i) {
                int row = wr * 64 + i * 16 + (lane & 15);
                int off = (ks * 64 + ((lane >> 4) * 16)) ^ ((row & SWM) << 4);
                av[i] = *(const short8v*)(smem + row * RB + off);
            }
            #pragma unroll
            for (int j = 0; j < 4; ++j) {
                int row = wc * 64 + j * 16 + (lane & 15);
                int off = (ks * 64 + ((lane >> 4) * 16)) ^ ((row & SWM) << 4);
                bv[j] = *(const short8v*)(smem + TILE_B + row * RB + off);
            }
            #pragma unroll
            for (int i = 0; i < 4; ++i)
                #pragma unroll
                for (int j = 0; j < 4; ++j)
                    acc[i][j] = __builtin_amdgcn_mfma_f32_16x16x32_bf16(av[i], bv[j], acc[i][j], 0, 0, 0);
        }
        __syncthreads();
    }
    #pragma unroll
    for (int i = 0; i < 4; ++i) {
        #pragma unroll
        for (int j = 0; j < 4; ++j) {
            int col = n0 + wc * 64 + j * 16 + (lane & 15);
            int rowb = m0 + wr * 64 + i * 16 + ((lane >> 4) * 4);
            float bv2 = bias[col];
            #pragma unroll
            for (int v = 0; v < 4; ++v)
                C[(size_t)(rowb + v) * N + col] = f2bf(acc[i][j][v] + bv2);
        }
    }
}

// ---------------- act epilogue (bf16 feat in): out = center + max_n(theta*support) --------
__global__ __launch_bounds__(256)
void act_kernel(const unsigned short* __restrict__ feat, const int* __restrict__ nbr,
                const float* __restrict__ diffn, const float* __restrict__ dmat,
                float* __restrict__ outp, unsigned short* __restrict__ outh,
                int Vv, int OC)
{
    int OC4 = OC >> 2;
    int t = blockIdx.x * 256 + threadIdx.x;
    int total = BS * Vv * OC4;
    if (t >= total) return;
    int c4 = t % OC4;
    int v = (t / OC4) % Vv;
    int b = t / (OC4 * Vv);
    const float4* d4 = (const float4*)dmat;
    float4 D0 = d4[c4], D1 = d4[OC4 + c4], D2 = d4[2 * OC4 + c4];
    float n0 = sqrtf(D0.x * D0.x + D1.x * D1.x + D2.x * D2.x);
    float n1 = sqrtf(D0.y * D0.y + D1.y * D1.y + D2.y * D2.y);
    float n2 = sqrtf(D0.z * D0.z + D1.z * D1.z + D2.z * D2.z);
    float n3 = sqrtf(D0.w * D0.w + D1.w * D1.w + D2.w * D2.w);
    float i0 = 1.0f / fmaxf(n0, 1e-12f);
    float i1 = 1.0f / fmaxf(n1, 1e-12f);
    float i2 = 1.0f / fmaxf(n2, 1e-12f);
    float i3 = 1.0f / fmaxf(n3, 1e-12f);
    D0.x *= i0; D0.y *= i1; D0.z *= i2; D0.w *= i3;
    D1.x *= i0; D1.y *= i1; D1.z *= i2; D1.w *= i3;
    D2.x *= i0; D2.y *= i1; D2.z *= i2; D2.w *= i3;

    const int* nb = nbr + ((size_t)b * Vv + v) * NB;
    const float* dfn = diffn + ((size_t)b * Vv + v) * NB * 3;
    const ushort4* frow = (const ushort4*)feat;
    size_t rowstride = (size_t)(2 * OC4);        // row = 2*OC bf16 = 2*OC4 ushort4
    const ushort4* fsup = frow + (size_t)b * Vv * rowstride + OC4 + c4;
    float4 m = make_float4(-FLT_MAX, -FLT_MAX, -FLT_MAX, -FLT_MAX);
    for (int n = 0; n < NB; ++n) {
        int idx = nb[n];
        float e0 = dfn[3 * n + 0], e1 = dfn[3 * n + 1], e2 = dfn[3 * n + 2];
        ushort4 s = fsup[(size_t)idx * rowstride];
        float th;
        th = e0 * D0.x + e1 * D1.x + e2 * D2.x; m.x = fmaxf(m.x, th * bf2f(s.x));
        th = e0 * D0.y + e1 * D1.y + e2 * D2.y; m.y = fmaxf(m.y, th * bf2f(s.y));
        th = e0 * D0.z + e1 * D1.z + e2 * D2.z; m.z = fmaxf(m.z, th * bf2f(s.z));
        th = e0 * D0.w + e1 * D1.w + e2 * D2.w; m.w = fmaxf(m.w, th * bf2f(s.w));
    }
    ushort4 cen = frow[(size_t)b * Vv * rowstride + (size_t)v * rowstride + c4];
    float4 r = make_float4(bf2f(cen.x) + m.x, bf2f(cen.y) + m.y,
                           bf2f(cen.z) + m.z, bf2f(cen.w) + m.w);
    size_t oidx = ((size_t)b * Vv + v) * OC4 + c4;
    ushort4 h;
    h.x = f2bf(r.x); h.y = f2bf(r.y); h.z = f2bf(r.z); h.w = f2bf(r.w);
    ((ushort4*)outh)[oidx] = h;
    if (outp) ((float4*)outp)[oidx] = r;
}

// ---------------- neighbor max-pool + stride-2 subsample (64 ch, bf16 in/out) ----------------
__global__ __launch_bounds__(256)
void pool_kernel(const ushort4* __restrict__ fmh, const int* __restrict__ nbr,
                 ushort4* __restrict__ outp)
{
    const int C4 = 16;   // 64/4
    int t = blockIdx.x * 256 + threadIdx.x;
    int total = BS * V2 * C4;
    if (t >= total) return;
    int c = t % C4;
    int v2 = (t / C4) % V2;
    int b = t / (C4 * V2);
    const int* nb = nbr + ((size_t)b * V1 + 2 * v2) * NB;
    float4 m = make_float4(-FLT_MAX, -FLT_MAX, -FLT_MAX, -FLT_MAX);
    for (int n = 0; n < NB; ++n) {
        int idx = nb[n];
        ushort4 s = fmh[((size_t)b * V1 + idx) * C4 + c];
        m.x = fmaxf(m.x, bf2f(s.x)); m.y = fmaxf(m.y, bf2f(s.y));
        m.z = fmaxf(m.z, bf2f(s.z)); m.w = fmaxf(m.w, bf2f(s.w));
    }
    ushort4 h;
    h.x = f2bf(m.x); h.y = f2bf(m.y); h.z = f2bf(m.z); h.w = f2bf(m.w);
    outp[((size_t)b * V2 + v2) * C4 + c] = h;
}

// ---------------- global max over vertices (two stage) ----------------
__global__ __launch_bounds__(256)
void gmax_part(const float* __restrict__ fm, float* __restrict__ part)
{
    int c = blockIdx.x * 256 + threadIdx.x;
    int ch = blockIdx.y;
    int b = blockIdx.z;
    float m = -FLT_MAX;
    for (int v = ch * 128; v < (ch + 1) * 128; ++v)
        m = fmaxf(m, fm[((size_t)b * V2 + v) * 1024 + c]);
    part[((size_t)b * 8 + ch) * 1024 + c] = m;
}

__global__ __launch_bounds__(256)
void gmax_final(const float* __restrict__ part, float* __restrict__ g)
{
    int t = blockIdx.x * 256 + threadIdx.x;
    if (t >= BS * 1024) return;
    int c = t % 1024, b = t / 1024;
    float m = -FLT_MAX;
    for (int ch = 0; ch < 8; ++ch)
        m = fmaxf(m, part[((size_t)b * 8 + ch) * 1024 + c]);
    g[t] = m;
}

// ---------------- fc1 split-K partial: hpart[b][kg][j] ----------------
__global__ __launch_bounds__(256)
void fc1_part(const float* __restrict__ g, const float* __restrict__ fc1w,
              float* __restrict__ hpart)
{
    int b = blockIdx.x, kg = blockIdx.y;    // 4 x 8
    int j = threadIdx.x;                    // 256
    __shared__ float gs[128];
    if (j < 128) gs[j] = g[(size_t)b * 1024 + kg * 128 + j];
    __syncthreads();
    float h = 0.0f;
    #pragma unroll 4
    for (int k = 0; k < 128; ++k)
        h = fmaf(gs[k], fc1w[(size_t)(kg * 128 + k) * 256 + j], h);
    hpart[((size_t)b * 8 + kg) * 256 + j] = h;
}

// ---------------- head finalize: bn+relu then fc2 ----------------
__global__ __launch_bounds__(256)
void head2_kernel(const float* __restrict__ hpart, const float* __restrict__ fc1b,
                  const float* __restrict__ bng, const float* __restrict__ bnb,
                  const float* __restrict__ fc2w, const float* __restrict__ fc2b,
                  float* __restrict__ outp)
{
    __shared__ float hs[256];
    __shared__ float part[4][40];
    int b = blockIdx.x;
    int j = threadIdx.x;
    float s = fc1b[j];
    #pragma unroll
    for (int kg = 0; kg < 8; ++kg) s += hpart[((size_t)b * 8 + kg) * 256 + j];
    const float rc = 0.99999500003749937f;   // rsqrt(1 + 1e-5)
    s = s * rc * bng[j] + bnb[j];
    hs[j] = fmaxf(s, 0.0f);
    __syncthreads();
    int ks = j >> 6, jo = j & 63;
    if (jo < 40) {
        float o = 0.0f;
        for (int k = ks * 64; k < ks * 64 + 64; ++k)
            o = fmaf(hs[k], fc2w[(size_t)k * 40 + jo], o);
        part[ks][jo] = o;
    }
    __syncthreads();
    if (j < 40)
        outp[(size_t)b * 40 + j] = fc2b[j] + part[0][j] + part[1][j] + part[2][j] + part[3][j];
}

// ---------------- host driver ----------------
extern "C" void kernel_launch(void* const* d_in, const int* in_sizes, int n_in,
                              void* d_out, int out_size, void* d_ws, size_t ws_size,
                              hipStream_t stream)
{
    (void)in_sizes; (void)n_in; (void)out_size; (void)ws_size;
    const float* verts = (const float*)d_in[0];
    auto Wp = [&](int i) { return (const float*)d_in[1 + 3 * i]; };
    auto Bp = [&](int i) { return (const float*)d_in[2 + 3 * i]; };
    auto Dp = [&](int i) { return (const float*)d_in[3 + 3 * i]; };
    const float* fc1w = (const float*)d_in[37];
    const float* fc1b = (const float*)d_in[38];
    const float* bng  = (const float*)d_in[39];
    const float* bnb  = (const float*)d_in[40];
    const float* fc2w = (const float*)d_in[41];
    const float* fc2b = (const float*)d_in[42];

    static const int IC[12] = {3, 32, 64, 64, 64, 64, 64, 128, 256, 1024, 1024, 1024};
    static const int OC[12] = {32, 64, 64, 64, 64, 64, 128, 256, 1024, 1024, 1024, 1024};

    char* ws = (char*)d_ws;
    size_t off = 0;
    auto alloc = [&](size_t bytes) {
        void* p = ws + off;
        off += (bytes + 255) & ~(size_t)255;
        return p;
    };
    int*   nbr1   = (int*)alloc((size_t)BS * V1 * NB * 4);
    int*   nbr2   = (int*)alloc((size_t)BS * V2 * NB * 4);
    float* diffn1 = (float*)alloc((size_t)BS * V1 * NB * 3 * 4);
    float* diffn2 = (float*)alloc((size_t)BS * V2 * NB * 3 * 4);
    unsigned short* feat = (unsigned short*)alloc((size_t)BS * V2 * 2048 * 2);  // 16.8 MB bf16
    unsigned short* fmh0 = (unsigned short*)alloc((size_t)BS * V2 * 1024 * 2);  // 8.4 MB
    unsigned short* fmh1 = (unsigned short*)alloc((size_t)BS * V2 * 1024 * 2);  // 8.4 MB
    float* fm32   = (float*)alloc((size_t)BS * V2 * 1024 * 4);           // 16.8 MB (c44 only)
    float* gpart  = (float*)alloc((size_t)BS * 8 * 1024 * 4);
    float* g      = (float*)alloc((size_t)BS * 1024 * 4);
    float* hpart  = (float*)alloc((size_t)BS * 8 * 256 * 4);

    // bf16 transposed weights per layer (layers 1..11)
    unsigned short* WtBuf[12];
    {
        size_t total = 0;
        for (int i = 1; i < 12; ++i) total += (size_t)(2 * OC[i]) * IC[i];
        unsigned short* base = (unsigned short*)alloc(total * 2);
        size_t o2 = 0;
        for (int i = 1; i < 12; ++i) { WtBuf[i] = base + o2; o2 += (size_t)(2 * OC[i]) * IC[i]; }
    }
    for (int i = 1; i < 12; ++i) {
        int K = IC[i], N = 2 * OC[i];
        dim3 gdim(N / 32, K / 32);
        convT_kernel<<<gdim, 256, 0, stream>>>(Wp(i), WtBuf[i], K, N);
    }

    auto gemm = [&](const unsigned short* A, int li, unsigned short* Cc, int M) {
        int K = IC[li], N = 2 * OC[li];
        dim3 gdim(N / 128, M / 128);
        if (K % 64 == 0)
            gemm_mfma<64><<<gdim, 256, 0, stream>>>(A, WtBuf[li], Bp(li), Cc, M, N, K);
        else
            gemm_mfma<32><<<gdim, 256, 0, stream>>>(A, WtBuf[li], Bp(li), Cc, M, N, K);
    };
    auto act = [&](const unsigned short* f, const int* nbr, const float* dfn, const float* d,
                   float* outp, unsigned short* outh, int Vv, int oc) {
        int total = BS * Vv * (oc / 4);
        act_kernel<<<(total + 255) / 256, 256, 0, stream>>>(f, nbr, dfn, d, outp, outh, Vv, oc);
    };

    // ---- stage 1: full-res kNN + diffs ----
    knn_wave_kernel<32><<<BS * V1 / 4, 256, 0, stream>>>(verts, 1, nbr1);
    diffn_kernel<<<(BS * V1 * NB + 255) / 256, 256, 0, stream>>>(verts, nbr1, V1, 1, diffn1);

    // ---- c0 (tiny GEMM, bf16 out) + act ----
    c0_kernel<<<(BS * V1 * 64 + 255) / 256, 256, 0, stream>>>(verts, Wp(0), Bp(0), feat);
    unsigned short* hb[2] = {fmh0, fmh1};
    int pb = 0;
    act(feat, nbr1, diffn1, Dp(0), nullptr, hb[pb], V1, OC[0]);
    const unsigned short* cur = hb[pb]; pb ^= 1;

    // ---- full-res conv layers (c1, c12, c13, c14, p1) ----
    for (int i = 1; i < 6; ++i) {
        gemm(cur, i, feat, BS * V1);
        act(feat, nbr1, diffn1, Dp(i), nullptr, hb[pb], V1, OC[i]);
        cur = hb[pb]; pb ^= 1;
    }

    // ---- pool (neighbor max at full res, subsample stride 2, bf16) ----
    {
        int total = BS * V2 * 16;
        pool_kernel<<<(total + 255) / 256, 256, 0, stream>>>(
            (const ushort4*)cur, nbr1, (ushort4*)hb[pb]);
        cur = hb[pb]; pb ^= 1;
    }

    // ---- stage 2: half-res kNN + diffs ----
    knn_wave_kernel<16><<<BS * V2 / 4, 256, 0, stream>>>(verts, 2, nbr2);
    diffn_kernel<<<(BS * V2 * NB + 255) / 256, 256, 0, stream>>>(verts, nbr2, V2, 2, diffn2);

    // ---- half-res conv layers (c2, c3, c4, c42, c43, c44) ----
    for (int i = 6; i < 12; ++i) {
        gemm(cur, i, feat, BS * V2);
        float* f32out = (i == 11) ? fm32 : nullptr;
        act(feat, nbr2, diffn2, Dp(i), f32out, hb[pb], V2, OC[i]);
        cur = hb[pb]; pb ^= 1;
    }

    // ---- head ----
    gmax_part<<<dim3(4, 8, BS), 256, 0, stream>>>(fm32, gpart);
    gmax_final<<<(BS * 1024 + 255) / 256, 256, 0, stream>>>(gpart, g);
    fc1_part<<<dim3(BS, 8), 256, 0, stream>>>(g, fc1w, hpart);
    head2_kernel<<<BS, 256, 0, stream>>>(hpart, fc1b, bng, bnb, fc2w, fc2b, (float*)d_out);
}

// Round 9
// 520.973 us; speedup vs baseline: 3.8285x; 1.1590x over previous
//
#include <hip/hip_runtime.h>
#include <float.h>
#include <math.h>

#define BS 4
#define V1 2048
#define V2 1024
#define NB 20
#define KSEL 21   // k+1: take 21 nearest, drop the nearest (self)

typedef __attribute__((ext_vector_type(8))) short short8v;   // 8 x bf16 bits (4 VGPRs)
typedef __attribute__((ext_vector_type(4))) float f32x4;

__device__ __forceinline__ unsigned short f2bf(float x) {
    union { float f; unsigned u; } v; v.f = x;
    unsigned r = (v.u + 0x7fffu + ((v.u >> 16) & 1u)) >> 16;   // RNE
    return (unsigned short)r;
}
__device__ __forceinline__ float bf2f(unsigned short h) {
    return __uint_as_float((unsigned)h << 16);
}
__device__ __forceinline__ unsigned umin32(unsigned a, unsigned b) { return a < b ? a : b; }

__device__ __forceinline__ void gload16(const void* g, void* l) {
    __builtin_amdgcn_global_load_lds((const __attribute__((address_space(1))) void*)g,
                                     (__attribute__((address_space(3))) void*)l, 16, 0, 0);
}

// ---------------- kNN: one WAVE per query; per-lane sorted top-4 cache ----------------
template<int SLOTS>
__global__ __launch_bounds__(256)
void knn_wave_kernel(const float* __restrict__ verts, int stride, int* __restrict__ nbr)
{
    constexpr int Vv = SLOTS * 64;
    __shared__ float xs[Vv], ys[Vv], zs[Vv];
    int tid = threadIdx.x;
    int lane = tid & 63;
    int wv = tid >> 6;                    // wave id 0..3
    int b = blockIdx.x / (Vv / 4);
    int q0 = (blockIdx.x % (Vv / 4)) * 4;
    const float* vb = verts + (size_t)b * V1 * 3;
    for (int p = tid; p < Vv; p += 256) {
        xs[p] = vb[(size_t)p * stride * 3 + 0];
        ys[p] = vb[(size_t)p * stride * 3 + 1];
        zs[p] = vb[(size_t)p * stride * 3 + 2];
    }
    __syncthreads();
    int i = q0 + wv;                      // this wave's query
    float xi = xs[i], yi = ys[i], zi = zs[i];
    float sqi = xi * xi + yi * yi + zi * zi;
    unsigned keys[SLOTS];
    #pragma unroll
    for (int s = 0; s < SLOTS; ++s) {
        int j = s * 64 + lane;
        float xj = xs[j], yj = ys[j], zj = zs[j];
        float sqj = xj * xj + yj * yj + zj * zj;
        float d = sqi - 2.0f * (xi * xj + yi * yj + zi * zj) + sqj;
        unsigned u = __float_as_uint(d);
        u = (u & 0x80000000u) ? ~u : (u | 0x80000000u);
        keys[s] = (u & ~31u) | (unsigned)s;
    }
    const unsigned UMAX = 0xFFFFFFFFu;
    unsigned c0 = UMAX, c1 = UMAX, c2 = UMAX, c3 = UMAX;
    #pragma unroll
    for (int s = 0; s < SLOTS; ++s) c0 = umin32(c0, keys[s]);
    #pragma unroll
    for (int s = 0; s < SLOTS; ++s) { unsigned k = keys[s]; if (k > c0) c1 = umin32(c1, k); }
    #pragma unroll
    for (int s = 0; s < SLOTS; ++s) { unsigned k = keys[s]; if (k > c1) c2 = umin32(c2, k); }
    #pragma unroll
    for (int s = 0; s < SLOTS; ++s) { unsigned k = keys[s]; if (k > c2) c3 = umin32(c3, k); }

    unsigned lm = c0;
    int* out = nbr + ((size_t)b * Vv + i) * NB;
    for (int it = 0; it < KSEL; ++it) {
        unsigned m = lm;
        #pragma unroll
        for (int off = 1; off < 64; off <<= 1)
            m = umin32(m, (unsigned)__shfl_xor((int)m, off));
        unsigned long long bal = __ballot(lm == m);
        int wl = __ffsll(bal) - 1;
        int slot = (int)(m & 31u);
        int j = slot * 64 + wl;
        if (it > 0 && lane == 0) out[it - 1] = j;
        if (lane == wl) {
            c0 = c1; c1 = c2; c2 = c3; c3 = UMAX;    // pop head
            if (c0 == UMAX) {                         // rare refill
                #pragma unroll
                for (int s = 0; s < SLOTS; ++s) {
                    unsigned k = keys[s];
                    if (k > m) c0 = umin32(c0, k);
                }
            }
            lm = c0;
        }
    }
}

// ---------------- normalized neighbor difference vectors ----------------
__global__ __launch_bounds__(256)
void diffn_kernel(const float* __restrict__ verts, const int* __restrict__ nbr,
                  int Vv, int stride, float* __restrict__ diffn)
{
    int t = blockIdx.x * 256 + threadIdx.x;
    int total = BS * Vv * NB;
    if (t >= total) return;
    int v = (t / NB) % Vv;
    int b = t / (NB * Vv);
    const float* vb = verts + (size_t)b * V1 * 3;
    int j = nbr[t];
    float xi = vb[(size_t)v * stride * 3 + 0];
    float yi = vb[(size_t)v * stride * 3 + 1];
    float zi = vb[(size_t)v * stride * 3 + 2];
    float dx = vb[(size_t)j * stride * 3 + 0] - xi;
    float dy = vb[(size_t)j * stride * 3 + 1] - yi;
    float dz = vb[(size_t)j * stride * 3 + 2] - zi;
    float nrm = sqrtf(dx * dx + dy * dy + dz * dz);
    float inv = 1.0f / fmaxf(nrm, 1e-12f);
    diffn[(size_t)t * 3 + 0] = dx * inv;
    diffn[(size_t)t * 3 + 1] = dy * inv;
    diffn[(size_t)t * 3 + 2] = dz * inv;
}

// ---------------- fused weight transpose + fp32->bf16 for all 11 layers ----------------
struct ConvTArgs {
    const float* W[11];
    unsigned short* Wt[11];
    int K[11];
    int N[11];
    int tileoff[12];
};

__global__ __launch_bounds__(256)
void convT_all(ConvTArgs a)
{
    __shared__ float t[32][33];
    int g = blockIdx.x;
    int L = 0;
    #pragma unroll
    for (int q = 0; q < 10; ++q) if (g >= a.tileoff[q + 1]) L = q + 1;
    int rel = g - a.tileoff[L];
    int K = a.K[L], N = a.N[L];
    int tilesN = N >> 5;
    int k0 = (rel / tilesN) << 5, n0 = (rel % tilesN) << 5;
    const float* W = a.W[L];
    unsigned short* Wt = a.Wt[L];
    int tx = threadIdx.x & 31, ty = threadIdx.x >> 5;   // ty 0..7
    #pragma unroll
    for (int r = ty; r < 32; r += 8) t[r][tx] = W[(size_t)(k0 + r) * N + n0 + tx];
    __syncthreads();
    #pragma unroll
    for (int r = ty; r < 32; r += 8) Wt[(size_t)(n0 + r) * K + k0 + tx] = f2bf(t[tx][r]);
}

// ---------------- c0: feat = verts @ W(3x64) + b (bf16 out) ----------------
__global__ __launch_bounds__(256)
void c0_kernel(const float* __restrict__ verts, const float* __restrict__ W,
               const float* __restrict__ Bv, unsigned short* __restrict__ feat)
{
    int t = blockIdx.x * 256 + threadIdx.x;
    if (t >= BS * V1 * 64) return;
    int n = t & 63, m = t >> 6;
    float x = verts[(size_t)m * 3 + 0];
    float y = verts[(size_t)m * 3 + 1];
    float z = verts[(size_t)m * 3 + 2];
    feat[t] = f2bf(x * W[n] + y * W[64 + n] + z * W[128 + n] + Bv[n]);
}

// ---------------- bf16 MFMA GEMM + bias: C(MxN bf16) = A(MxK) @ Wt(NxK)^T + bias --------
// 4 waves (2x2); per-wave tile (BM/2)x(BN/2); XCD-chunked block swizzle (T1).
template<int BK, int BM, int BN>
__global__ __launch_bounds__(256)
void gemm_mfma(const unsigned short* __restrict__ A, const unsigned short* __restrict__ Wt,
               const float* __restrict__ bias, unsigned short* __restrict__ C,
               int M, int N, int K)
{
    constexpr int RB = BK * 2;               // row bytes
    constexpr int TA = BM * RB;
    constexpr int TB = BN * RB;
    constexpr int SWM = (BK == 64) ? 7 : 3;  // swizzle row mask
    constexpr int FI = BM / 32, FJ = BN / 32;
    constexpr int RA = TA / 4096, RBN = TB / 4096;
    constexpr int RMAX = (RA > RBN) ? RA : RBN;
    __shared__ __align__(16) char smem[TA + TB];
    int tid = threadIdx.x;
    int lane = tid & 63, wid = tid >> 6;
    int wr = wid >> 1, wc = wid & 1;

    // T1: bijective chunked XCD swizzle (all our grids have nwg % 8 == 0)
    int nwg = gridDim.x * gridDim.y;
    int orig = blockIdx.y * gridDim.x + blockIdx.x;
    int wg = orig;
    if ((nwg & 7) == 0) wg = (orig & 7) * (nwg >> 3) + (orig >> 3);
    int m0 = (wg / gridDim.x) * BM;
    int n0 = (wg % gridDim.x) * BN;

    f32x4 acc[FI][FJ] = {};

    int srow[RMAX], soffe[RMAX];
    #pragma unroll
    for (int r = 0; r < RMAX; ++r) {
        int L = r * 4096 + tid * 16;
        int row = L / RB;
        int off = (L % RB) ^ ((row & SWM) << 4);
        srow[r] = row; soffe[r] = off >> 1;
    }

    for (int kt = 0; kt < K; kt += BK) {
        #pragma unroll
        for (int r = 0; r < RA; ++r)
            gload16(A + (size_t)(m0 + srow[r]) * K + kt + soffe[r],
                    smem + r * 4096 + wid * 1024);
        #pragma unroll
        for (int r = 0; r < RBN; ++r)
            gload16(Wt + (size_t)(n0 + srow[r]) * K + kt + soffe[r],
                    smem + TA + r * 4096 + wid * 1024);
        asm volatile("s_waitcnt vmcnt(0)" ::: "memory");
        __syncthreads();
        #pragma unroll
        for (int ks = 0; ks < BK / 32; ++ks) {
            short8v av[FI], bv[FJ];
            #pragma unroll
            for (int i = 0; i < FI; ++i) {
                int row = wr * (BM / 2) + i * 16 + (lane & 15);
                int off = (ks * 64 + ((lane >> 4) * 16)) ^ ((row & SWM) << 4);
                av[i] = *(const short8v*)(smem + row * RB + off);
            }
            #pragma unroll
            for (int j = 0; j < FJ; ++j) {
                int row = wc * (BN / 2) + j * 16 + (lane & 15);
                int off = (ks * 64 + ((lane >> 4) * 16)) ^ ((row & SWM) << 4);
                bv[j] = *(const short8v*)(smem + TA + row * RB + off);
            }
            #pragma unroll
            for (int i = 0; i < FI; ++i)
                #pragma unroll
                for (int j = 0; j < FJ; ++j)
                    acc[i][j] = __builtin_amdgcn_mfma_f32_16x16x32_bf16(av[i], bv[j], acc[i][j], 0, 0, 0);
        }
        __syncthreads();
    }
    #pragma unroll
    for (int i = 0; i < FI; ++i) {
        #pragma unroll
        for (int j = 0; j < FJ; ++j) {
            int col = n0 + wc * (BN / 2) + j * 16 + (lane & 15);
            int rowb = m0 + wr * (BM / 2) + i * 16 + ((lane >> 4) * 4);
            float bv2 = bias[col];
            #pragma unroll
            for (int v = 0; v < 4; ++v)
                C[(size_t)(rowb + v) * N + col] = f2bf(acc[i][j][v] + bv2);
        }
    }
}

// ---------------- generic act epilogue (bf16 feat): out = center + max_n(theta*support) ----
__global__ __launch_bounds__(256)
void act_kernel(const unsigned short* __restrict__ feat, const int* __restrict__ nbr,
                const float* __restrict__ diffn, const float* __restrict__ dmat,
                float* __restrict__ outp, unsigned short* __restrict__ outh,
                int Vv, int OC)
{
    int OC4 = OC >> 2;
    int t = blockIdx.x * 256 + threadIdx.x;
    int total = BS * Vv * OC4;
    if (t >= total) return;
    int c4 = t % OC4;
    int v = (t / OC4) % Vv;
    int b = t / (OC4 * Vv);
    const float4* d4 = (const float4*)dmat;
    float4 D0 = d4[c4], D1 = d4[OC4 + c4], D2 = d4[2 * OC4 + c4];
    float n0 = sqrtf(D0.x * D0.x + D1.x * D1.x + D2.x * D2.x);
    float n1 = sqrtf(D0.y * D0.y + D1.y * D1.y + D2.y * D2.y);
    float n2 = sqrtf(D0.z * D0.z + D1.z * D1.z + D2.z * D2.z);
    float n3 = sqrtf(D0.w * D0.w + D1.w * D1.w + D2.w * D2.w);
    float i0 = 1.0f / fmaxf(n0, 1e-12f);
    float i1 = 1.0f / fmaxf(n1, 1e-12f);
    float i2 = 1.0f / fmaxf(n2, 1e-12f);
    float i3 = 1.0f / fmaxf(n3, 1e-12f);
    D0.x *= i0; D0.y *= i1; D0.z *= i2; D0.w *= i3;
    D1.x *= i0; D1.y *= i1; D1.z *= i2; D1.w *= i3;
    D2.x *= i0; D2.y *= i1; D2.z *= i2; D2.w *= i3;

    const int* nb = nbr + ((size_t)b * Vv + v) * NB;
    const float* dfn = diffn + ((size_t)b * Vv + v) * NB * 3;
    const ushort4* frow = (const ushort4*)feat;
    size_t rowstride = (size_t)(2 * OC4);
    const ushort4* fsup = frow + (size_t)b * Vv * rowstride + OC4 + c4;
    float4 m = make_float4(-FLT_MAX, -FLT_MAX, -FLT_MAX, -FLT_MAX);
    for (int n = 0; n < NB; ++n) {
        int idx = nb[n];
        float e0 = dfn[3 * n + 0], e1 = dfn[3 * n + 1], e2 = dfn[3 * n + 2];
        ushort4 s = fsup[(size_t)idx * rowstride];
        float th;
        th = e0 * D0.x + e1 * D1.x + e2 * D2.x; m.x = fmaxf(m.x, th * bf2f(s.x));
        th = e0 * D0.y + e1 * D1.y + e2 * D2.y; m.y = fmaxf(m.y, th * bf2f(s.y));
        th = e0 * D0.z + e1 * D1.z + e2 * D2.z; m.z = fmaxf(m.z, th * bf2f(s.z));
        th = e0 * D0.w + e1 * D1.w + e2 * D2.w; m.w = fmaxf(m.w, th * bf2f(s.w));
    }
    ushort4 cen = frow[(size_t)b * Vv * rowstride + (size_t)v * rowstride + c4];
    float4 r = make_float4(bf2f(cen.x) + m.x, bf2f(cen.y) + m.y,
                           bf2f(cen.z) + m.z, bf2f(cen.w) + m.w);
    size_t oidx = ((size_t)b * Vv + v) * OC4 + c4;
    ushort4 h;
    h.x = f2bf(r.x); h.y = f2bf(r.y); h.z = f2bf(r.z); h.w = f2bf(r.w);
    ((ushort4*)outh)[oidx] = h;
    if (outp) ((float4*)outp)[oidx] = r;
}

// ---------------- act for OC=1024 @ V2 with XCD batch-clustering ----------------
// block g -> b=(g&7)>>1 pins batch b to XCD pair {2b,2b+1}; per-batch support (2MB) stays L2.
__global__ __launch_bounds__(256)
void act1024_kernel(const unsigned short* __restrict__ feat, const int* __restrict__ nbr,
                    const float* __restrict__ diffn, const float* __restrict__ dmat,
                    float* __restrict__ outp, unsigned short* __restrict__ outh)
{
    const int OC4 = 256;
    int g = blockIdx.x;                       // 4096 blocks
    int b = (g & 7) >> 1;
    int v = ((g >> 3) << 1) | (g & 1);
    int c4 = threadIdx.x;                     // 0..255
    const float4* d4 = (const float4*)dmat;
    float4 D0 = d4[c4], D1 = d4[OC4 + c4], D2 = d4[2 * OC4 + c4];
    float n0 = sqrtf(D0.x * D0.x + D1.x * D1.x + D2.x * D2.x);
    float n1 = sqrtf(D0.y * D0.y + D1.y * D1.y + D2.y * D2.y);
    float n2 = sqrtf(D0.z * D0.z + D1.z * D1.z + D2.z * D2.z);
    float n3 = sqrtf(D0.w * D0.w + D1.w * D1.w + D2.w * D2.w);
    float i0 = 1.0f / fmaxf(n0, 1e-12f);
    float i1 = 1.0f / fmaxf(n1, 1e-12f);
    float i2 = 1.0f / fmaxf(n2, 1e-12f);
    float i3 = 1.0f / fmaxf(n3, 1e-12f);
    D0.x *= i0; D0.y *= i1; D0.z *= i2; D0.w *= i3;
    D1.x *= i0; D1.y *= i1; D1.z *= i2; D1.w *= i3;
    D2.x *= i0; D2.y *= i1; D2.z *= i2; D2.w *= i3;

    const int* nb = nbr + ((size_t)b * V2 + v) * NB;
    const float* dfn = diffn + ((size_t)b * V2 + v) * NB * 3;
    const ushort4* frow = (const ushort4*)feat;
    const size_t rowstride = 2 * OC4;         // 512 ushort4 per feat row
    const ushort4* fsup = frow + (size_t)b * V2 * rowstride + OC4 + c4;
    float4 m = make_float4(-FLT_MAX, -FLT_MAX, -FLT_MAX, -FLT_MAX);
    for (int n = 0; n < NB; ++n) {
        int idx = nb[n];
        float e0 = dfn[3 * n + 0], e1 = dfn[3 * n + 1], e2 = dfn[3 * n + 2];
        ushort4 s = fsup[(size_t)idx * rowstride];
        float th;
        th = e0 * D0.x + e1 * D1.x + e2 * D2.x; m.x = fmaxf(m.x, th * bf2f(s.x));
        th = e0 * D0.y + e1 * D1.y + e2 * D2.y; m.y = fmaxf(m.y, th * bf2f(s.y));
        th = e0 * D0.z + e1 * D1.z + e2 * D2.z; m.z = fmaxf(m.z, th * bf2f(s.z));
        th = e0 * D0.w + e1 * D1.w + e2 * D2.w; m.w = fmaxf(m.w, th * bf2f(s.w));
    }
    ushort4 cen = frow[((size_t)b * V2 + v) * rowstride + c4];
    float4 r = make_float4(bf2f(cen.x) + m.x, bf2f(cen.y) + m.y,
                           bf2f(cen.z) + m.z, bf2f(cen.w) + m.w);
    size_t oidx = ((size_t)b * V2 + v) * OC4 + c4;
    ushort4 h;
    h.x = f2bf(r.x); h.y = f2bf(r.y); h.z = f2bf(r.z); h.w = f2bf(r.w);
    ((ushort4*)outh)[oidx] = h;
    if (outp) ((float4*)outp)[oidx] = r;
}

// ---------------- neighbor max-pool + stride-2 subsample (64 ch, bf16 in/out) ----------------
__global__ __launch_bounds__(256)
void pool_kernel(const ushort4* __restrict__ fmh, const int* __restrict__ nbr,
                 ushort4* __restrict__ outp)
{
    const int C4 = 16;   // 64/4
    int t = blockIdx.x * 256 + threadIdx.x;
    int total = BS * V2 * C4;
    if (t >= total) return;
    int c = t % C4;
    int v2 = (t / C4) % V2;
    int b = t / (C4 * V2);
    const int* nb = nbr + ((size_t)b * V1 + 2 * v2) * NB;
    float4 m = make_float4(-FLT_MAX, -FLT_MAX, -FLT_MAX, -FLT_MAX);
    for (int n = 0; n < NB; ++n) {
        int idx = nb[n];
        ushort4 s = fmh[((size_t)b * V1 + idx) * C4 + c];
        m.x = fmaxf(m.x, bf2f(s.x)); m.y = fmaxf(m.y, bf2f(s.y));
        m.z = fmaxf(m.z, bf2f(s.z)); m.w = fmaxf(m.w, bf2f(s.w));
    }
    ushort4 h;
    h.x = f2bf(m.x); h.y = f2bf(m.y); h.z = f2bf(m.z); h.w = f2bf(m.w);
    outp[((size_t)b * V2 + v2) * C4 + c] = h;
}

// ---------------- global max over vertices (two stage) ----------------
__global__ __launch_bounds__(256)
void gmax_part(const float* __restrict__ fm, float* __restrict__ part)
{
    int c = blockIdx.x * 256 + threadIdx.x;
    int ch = blockIdx.y;
    int b = blockIdx.z;
    float m = -FLT_MAX;
    for (int v = ch * 128; v < (ch + 1) * 128; ++v)
        m = fmaxf(m, fm[((size_t)b * V2 + v) * 1024 + c]);
    part[((size_t)b * 8 + ch) * 1024 + c] = m;
}

__global__ __launch_bounds__(256)
void gmax_final(const float* __restrict__ part, float* __restrict__ g)
{
    int t = blockIdx.x * 256 + threadIdx.x;
    if (t >= BS * 1024) return;
    int c = t % 1024, b = t / 1024;
    float m = -FLT_MAX;
    for (int ch = 0; ch < 8; ++ch)
        m = fmaxf(m, part[((size_t)b * 8 + ch) * 1024 + c]);
    g[t] = m;
}

// ---------------- fc1 split-K partial: hpart[b][kg][j] ----------------
__global__ __launch_bounds__(256)
void fc1_part(const float* __restrict__ g, const float* __restrict__ fc1w,
              float* __restrict__ hpart)
{
    int b = blockIdx.x, kg = blockIdx.y;    // 4 x 8
    int j = threadIdx.x;                    // 256
    __shared__ float gs[128];
    if (j < 128) gs[j] = g[(size_t)b * 1024 + kg * 128 + j];
    __syncthreads();
    float h = 0.0f;
    #pragma unroll 4
    for (int k = 0; k < 128; ++k)
        h = fmaf(gs[k], fc1w[(size_t)(kg * 128 + k) * 256 + j], h);
    hpart[((size_t)b * 8 + kg) * 256 + j] = h;
}

// ---------------- head finalize: bn+relu then fc2 ----------------
__global__ __launch_bounds__(256)
void head2_kernel(const float* __restrict__ hpart, const float* __restrict__ fc1b,
                  const float* __restrict__ bng, const float* __restrict__ bnb,
                  const float* __restrict__ fc2w, const float* __restrict__ fc2b,
                  float* __restrict__ outp)
{
    __shared__ float hs[256];
    __shared__ float part[4][40];
    int b = blockIdx.x;
    int j = threadIdx.x;
    float s = fc1b[j];
    #pragma unroll
    for (int kg = 0; kg < 8; ++kg) s += hpart[((size_t)b * 8 + kg) * 256 + j];
    const float rc = 0.99999500003749937f;   // rsqrt(1 + 1e-5)
    s = s * rc * bng[j] + bnb[j];
    hs[j] = fmaxf(s, 0.0f);
    __syncthreads();
    int ks = j >> 6, jo = j & 63;
    if (jo < 40) {
        float o = 0.0f;
        for (int k = ks * 64; k < ks * 64 + 64; ++k)
            o = fmaf(hs[k], fc2w[(size_t)k * 40 + jo], o);
        part[ks][jo] = o;
    }
    __syncthreads();
    if (j < 40)
        outp[(size_t)b * 40 + j] = fc2b[j] + part[0][j] + part[1][j] + part[2][j] + part[3][j];
}

// ---------------- host driver ----------------
extern "C" void kernel_launch(void* const* d_in, const int* in_sizes, int n_in,
                              void* d_out, int out_size, void* d_ws, size_t ws_size,
                              hipStream_t stream)
{
    (void)in_sizes; (void)n_in; (void)out_size; (void)ws_size;
    const float* verts = (const float*)d_in[0];
    auto Wp = [&](int i) { return (const float*)d_in[1 + 3 * i]; };
    auto Bp = [&](int i) { return (const float*)d_in[2 + 3 * i]; };
    auto Dp = [&](int i) { return (const float*)d_in[3 + 3 * i]; };
    const float* fc1w = (const float*)d_in[37];
    const float* fc1b = (const float*)d_in[38];
    const float* bng  = (const float*)d_in[39];
    const float* bnb  = (const float*)d_in[40];
    const float* fc2w = (const float*)d_in[41];
    const float* fc2b = (const float*)d_in[42];

    static const int IC[12] = {3, 32, 64, 64, 64, 64, 64, 128, 256, 1024, 1024, 1024};
    static const int OC[12] = {32, 64, 64, 64, 64, 64, 128, 256, 1024, 1024, 1024, 1024};

    char* ws = (char*)d_ws;
    size_t off = 0;
    auto alloc = [&](size_t bytes) {
        void* p = ws + off;
        off += (bytes + 255) & ~(size_t)255;
        return p;
    };
    int*   nbr1   = (int*)alloc((size_t)BS * V1 * NB * 4);
    int*   nbr2   = (int*)alloc((size_t)BS * V2 * NB * 4);
    float* diffn1 = (float*)alloc((size_t)BS * V1 * NB * 3 * 4);
    float* diffn2 = (float*)alloc((size_t)BS * V2 * NB * 3 * 4);
    unsigned short* feat = (unsigned short*)alloc((size_t)BS * V2 * 2048 * 2);  // 16.8 MB bf16
    unsigned short* fmh0 = (unsigned short*)alloc((size_t)BS * V2 * 1024 * 2);  // 8.4 MB
    unsigned short* fmh1 = (unsigned short*)alloc((size_t)BS * V2 * 1024 * 2);  // 8.4 MB
    float* fm32   = (float*)alloc((size_t)BS * V2 * 1024 * 4);           // 16.8 MB (c44 only)
    float* gpart  = (float*)alloc((size_t)BS * 8 * 1024 * 4);
    float* g      = (float*)alloc((size_t)BS * 1024 * 4);
    float* hpart  = (float*)alloc((size_t)BS * 8 * 256 * 4);

    // bf16 transposed weights per layer (layers 1..11)
    unsigned short* WtBuf[12];
    {
        size_t total = 0;
        for (int i = 1; i < 12; ++i) total += (size_t)(2 * OC[i]) * IC[i];
        unsigned short* base = (unsigned short*)alloc(total * 2);
        size_t o2 = 0;
        for (int i = 1; i < 12; ++i) { WtBuf[i] = base + o2; o2 += (size_t)(2 * OC[i]) * IC[i]; }
    }
    {
        ConvTArgs a;
        int toff = 0;
        for (int i = 1; i < 12; ++i) {
            int K = IC[i], N = 2 * OC[i];
            a.W[i - 1] = Wp(i);
            a.Wt[i - 1] = WtBuf[i];
            a.K[i - 1] = K;
            a.N[i - 1] = N;
            a.tileoff[i - 1] = toff;
            toff += (K / 32) * (N / 32);
        }
        a.tileoff[11] = toff;
        convT_all<<<toff, 256, 0, stream>>>(a);
    }

    auto gemm = [&](const unsigned short* A, int li, unsigned short* Cc, int M) {
        int K = IC[li], N = 2 * OC[li];
        if (N >= 1024) {
            dim3 gdim(N / 128, M / 128);
            gemm_mfma<64, 128, 128><<<gdim, 256, 0, stream>>>(A, WtBuf[li], Bp(li), Cc, M, N, K);
        } else if (K % 64 == 0) {
            dim3 gdim(N / 64, M / 64);
            gemm_mfma<64, 64, 64><<<gdim, 256, 0, stream>>>(A, WtBuf[li], Bp(li), Cc, M, N, K);
        } else {
            dim3 gdim(N / 64, M / 64);
            gemm_mfma<32, 64, 64><<<gdim, 256, 0, stream>>>(A, WtBuf[li], Bp(li), Cc, M, N, K);
        }
    };
    auto act = [&](const unsigned short* f, const int* nbr, const float* dfn, const float* d,
                   float* outp, unsigned short* outh, int Vv, int oc) {
        if (oc == 1024) {
            act1024_kernel<<<BS * V2, 256, 0, stream>>>(f, nbr, dfn, d, outp, outh);
        } else {
            int total = BS * Vv * (oc / 4);
            act_kernel<<<(total + 255) / 256, 256, 0, stream>>>(f, nbr, dfn, d, outp, outh, Vv, oc);
        }
    };

    // ---- stage 1: full-res kNN + diffs ----
    knn_wave_kernel<32><<<BS * V1 / 4, 256, 0, stream>>>(verts, 1, nbr1);
    diffn_kernel<<<(BS * V1 * NB + 255) / 256, 256, 0, stream>>>(verts, nbr1, V1, 1, diffn1);

    // ---- c0 (tiny GEMM, bf16 out) + act ----
    c0_kernel<<<(BS * V1 * 64 + 255) / 256, 256, 0, stream>>>(verts, Wp(0), Bp(0), feat);
    unsigned short* hb[2] = {fmh0, fmh1};
    int pb = 0;
    act(feat, nbr1, diffn1, Dp(0), nullptr, hb[pb], V1, OC[0]);
    const unsigned short* cur = hb[pb]; pb ^= 1;

    // ---- full-res conv layers (c1, c12, c13, c14, p1) ----
    for (int i = 1; i < 6; ++i) {
        gemm(cur, i, feat, BS * V1);
        act(feat, nbr1, diffn1, Dp(i), nullptr, hb[pb], V1, OC[i]);
        cur = hb[pb]; pb ^= 1;
    }

    // ---- pool (neighbor max at full res, subsample stride 2, bf16) ----
    {
        int total = BS * V2 * 16;
        pool_kernel<<<(total + 255) / 256, 256, 0, stream>>>(
            (const ushort4*)cur, nbr1, (ushort4*)hb[pb]);
        cur = hb[pb]; pb ^= 1;
    }

    // ---- stage 2: half-res kNN + diffs ----
    knn_wave_kernel<16><<<BS * V2 / 4, 256, 0, stream>>>(verts, 2, nbr2);
    diffn_kernel<<<(BS * V2 * NB + 255) / 256, 256, 0, stream>>>(verts, nbr2, V2, 2, diffn2);

    // ---- half-res conv layers (c2, c3, c4, c42, c43, c44) ----
    for (int i = 6; i < 12; ++i) {
        gemm(cur, i, feat, BS * V2);
        float* f32out = (i == 11) ? fm32 : nullptr;
        act(feat, nbr2, diffn2, Dp(i), f32out, hb[pb], V2, OC[i]);
        cur = hb[pb]; pb ^= 1;
    }

    // ---- head ----
    gmax_part<<<dim3(4, 8, BS), 256, 0, stream>>>(fm32, gpart);
    gmax_final<<<(BS * 1024 + 255) / 256, 256, 0, stream>>>(gpart, g);
    fc1_part<<<dim3(BS, 8), 256, 0, stream>>>(g, fc1w, hpart);
    head2_kernel<<<BS, 256, 0, stream>>>(hpart, fc1b, bng, bnb, fc2w, fc2b, (float*)d_out);
}

// Round 13
// 516.331 us; speedup vs baseline: 3.8629x; 1.0090x over previous
//
#include <hip/hip_runtime.h>
#include <float.h>
#include <math.h>

#define BS 4
#define V1 2048
#define V2 1024
#define NB 20
#define KSEL 21   // k+1: take 21 nearest, drop the nearest (self)

typedef __attribute__((ext_vector_type(8))) short short8v;   // 8 x bf16 bits (4 VGPRs)
typedef __attribute__((ext_vector_type(4))) float f32x4;

__device__ __forceinline__ unsigned short f2bf(float x) {
    union { float f; unsigned u; } v; v.f = x;
    unsigned r = (v.u + 0x7fffu + ((v.u >> 16) & 1u)) >> 16;   // RNE
    return (unsigned short)r;
}
__device__ __forceinline__ float bf2f(unsigned short h) {
    return __uint_as_float((unsigned)h << 16);
}
__device__ __forceinline__ unsigned umin32(unsigned a, unsigned b) { return a < b ? a : b; }

__device__ __forceinline__ void gload16(const void* g, void* l) {
    __builtin_amdgcn_global_load_lds((const __attribute__((address_space(1))) void*)g,
                                     (__attribute__((address_space(3))) void*)l, 16, 0, 0);
}

// ---------------- kNN + diffn fused: one WAVE per query; per-lane sorted top-4 cache ------
// key = (monotonic_dist & ~31) | slot ; candidate j = slot*64 + lane
template<int SLOTS>
__global__ __launch_bounds__(256)
void knn_wave_kernel(const float* __restrict__ verts, int stride, int* __restrict__ nbr,
                     float* __restrict__ diffn)
{
    constexpr int Vv = SLOTS * 64;
    __shared__ float xs[Vv], ys[Vv], zs[Vv];
    int tid = threadIdx.x;
    int lane = tid & 63;
    int wv = tid >> 6;                    // wave id 0..3
    int b = blockIdx.x / (Vv / 4);
    int q0 = (blockIdx.x % (Vv / 4)) * 4;
    const float* vb = verts + (size_t)b * V1 * 3;
    for (int p = tid; p < Vv; p += 256) {
        xs[p] = vb[(size_t)p * stride * 3 + 0];
        ys[p] = vb[(size_t)p * stride * 3 + 1];
        zs[p] = vb[(size_t)p * stride * 3 + 2];
    }
    __syncthreads();
    int i = q0 + wv;                      // this wave's query
    float xi = xs[i], yi = ys[i], zi = zs[i];
    float sqi = xi * xi + yi * yi + zi * zi;
    unsigned keys[SLOTS];
    #pragma unroll
    for (int s = 0; s < SLOTS; ++s) {
        int j = s * 64 + lane;
        float xj = xs[j], yj = ys[j], zj = zs[j];
        float sqj = xj * xj + yj * yj + zj * zj;
        float d = sqi - 2.0f * (xi * xj + yi * yj + zi * zj) + sqj;
        unsigned u = __float_as_uint(d);
        u = (u & 0x80000000u) ? ~u : (u | 0x80000000u);
        keys[s] = (u & ~31u) | (unsigned)s;
    }
    const unsigned UMAX = 0xFFFFFFFFu;
    unsigned c0 = UMAX, c1 = UMAX, c2 = UMAX, c3 = UMAX;
    #pragma unroll
    for (int s = 0; s < SLOTS; ++s) c0 = umin32(c0, keys[s]);
    #pragma unroll
    for (int s = 0; s < SLOTS; ++s) { unsigned k = keys[s]; if (k > c0) c1 = umin32(c1, k); }
    #pragma unroll
    for (int s = 0; s < SLOTS; ++s) { unsigned k = keys[s]; if (k > c1) c2 = umin32(c2, k); }
    #pragma unroll
    for (int s = 0; s < SLOTS; ++s) { unsigned k = keys[s]; if (k > c2) c3 = umin32(c3, k); }

    unsigned lm = c0;
    int myj = 0;
    for (int it = 0; it < KSEL; ++it) {
        unsigned m = lm;
        #pragma unroll
        for (int off = 1; off < 64; off <<= 1)
            m = umin32(m, (unsigned)__shfl_xor((int)m, off));
        unsigned long long bal = __ballot(lm == m);
        int wl = __ffsll(bal) - 1;
        int slot = (int)(m & 31u);
        int j = slot * 64 + wl;
        if (lane == it - 1) myj = j;               // lanes 0..19 capture winners 1..20
        if (lane == wl) {
            c0 = c1; c1 = c2; c2 = c3; c3 = UMAX;  // pop head
            if (c0 == UMAX) {                      // rare refill
                #pragma unroll
                for (int s = 0; s < SLOTS; ++s) {
                    unsigned k = keys[s];
                    if (k > m) c0 = umin32(c0, k);
                }
            }
            lm = c0;
        }
    }
    if (lane < NB) {
        nbr[((size_t)b * Vv + i) * NB + lane] = myj;
        float dx = xs[myj] - xi, dy = ys[myj] - yi, dz = zs[myj] - zi;
        float nrm = sqrtf(dx * dx + dy * dy + dz * dz);
        float inv = 1.0f / fmaxf(nrm, 1e-12f);
        float* dout = diffn + (((size_t)b * Vv + i) * NB + lane) * 3;
        dout[0] = dx * inv; dout[1] = dy * inv; dout[2] = dz * inv;
    }
}

// ---------------- fused weight transpose + fp32->bf16 for all 11 layers ----------------
struct ConvTArgs {
    const float* W[11];
    unsigned short* Wt[11];
    int K[11];
    int N[11];
    int tileoff[12];
};

__global__ __launch_bounds__(256)
void convT_all(ConvTArgs a)
{
    __shared__ float t[32][33];
    int g = blockIdx.x;
    int L = 0;
    #pragma unroll
    for (int q = 0; q < 10; ++q) if (g >= a.tileoff[q + 1]) L = q + 1;
    int rel = g - a.tileoff[L];
    int K = a.K[L], N = a.N[L];
    int tilesN = N >> 5;
    int k0 = (rel / tilesN) << 5, n0 = (rel % tilesN) << 5;
    const float* W = a.W[L];
    unsigned short* Wt = a.Wt[L];
    int tx = threadIdx.x & 31, ty = threadIdx.x >> 5;   // ty 0..7
    #pragma unroll
    for (int r = ty; r < 32; r += 8) t[r][tx] = W[(size_t)(k0 + r) * N + n0 + tx];
    __syncthreads();
    #pragma unroll
    for (int r = ty; r < 32; r += 8) Wt[(size_t)(n0 + r) * K + k0 + tx] = f2bf(t[tx][r]);
}

// ---------------- c0: feat = verts @ W(3x64) + b (bf16 out) ----------------
__global__ __launch_bounds__(256)
void c0_kernel(const float* __restrict__ verts, const float* __restrict__ W,
               const float* __restrict__ Bv, unsigned short* __restrict__ feat)
{
    int t = blockIdx.x * 256 + threadIdx.x;
    if (t >= BS * V1 * 64) return;
    int n = t & 63, m = t >> 6;
    float x = verts[(size_t)m * 3 + 0];
    float y = verts[(size_t)m * 3 + 1];
    float z = verts[(size_t)m * 3 + 2];
    feat[t] = f2bf(x * W[n] + y * W[64 + n] + z * W[128 + n] + Bv[n]);
}

// ---------------- bf16 MFMA GEMM + bias: C(MxN bf16) = A(MxK) @ Wt(NxK)^T + bias --------
// 4 waves (2x2); per-wave tile (BM/2)x(BN/2); XCD-chunked block swizzle (T1).
template<int BK, int BM, int BN>
__global__ __launch_bounds__(256)
void gemm_mfma(const unsigned short* __restrict__ A, const unsigned short* __restrict__ Wt,
               const float* __restrict__ bias, unsigned short* __restrict__ C,
               int M, int N, int K)
{
    constexpr int RB = BK * 2;               // row bytes
    constexpr int TA = BM * RB;
    constexpr int TB = BN * RB;
    constexpr int SWM = (BK == 64) ? 7 : 3;  // swizzle row mask
    constexpr int FI = BM / 32, FJ = BN / 32;
    constexpr int RA = TA / 4096, RBN = TB / 4096;
    constexpr int RMAX = (RA > RBN) ? RA : RBN;
    __shared__ __align__(16) char smem[TA + TB];
    int tid = threadIdx.x;
    int lane = tid & 63, wid = tid >> 6;
    int wr = wid >> 1, wc = wid & 1;

    // T1: bijective chunked XCD swizzle (all our grids have nwg % 8 == 0)
    int nwg = gridDim.x * gridDim.y;
    int orig = blockIdx.y * gridDim.x + blockIdx.x;
    int wg = orig;
    if ((nwg & 7) == 0) wg = (orig & 7) * (nwg >> 3) + (orig >> 3);
    int m0 = (wg / gridDim.x) * BM;
    int n0 = (wg % gridDim.x) * BN;

    f32x4 acc[FI][FJ] = {};

    int srow[RMAX], soffe[RMAX];
    #pragma unroll
    for (int r = 0; r < RMAX; ++r) {
        int L = r * 4096 + tid * 16;
        int row = L / RB;
        int off = (L % RB) ^ ((row & SWM) << 4);
        srow[r] = row; soffe[r] = off >> 1;
    }

    for (int kt = 0; kt < K; kt += BK) {
        #pragma unroll
        for (int r = 0; r < RA; ++r)
            gload16(A + (size_t)(m0 + srow[r]) * K + kt + soffe[r],
                    smem + r * 4096 + wid * 1024);
        #pragma unroll
        for (int r = 0; r < RBN; ++r)
            gload16(Wt + (size_t)(n0 + srow[r]) * K + kt + soffe[r],
                    smem + TA + r * 4096 + wid * 1024);
        asm volatile("s_waitcnt vmcnt(0)" ::: "memory");
        __syncthreads();
        #pragma unroll
        for (int ks = 0; ks < BK / 32; ++ks) {
            short8v av[FI], bv[FJ];
            #pragma unroll
            for (int i = 0; i < FI; ++i) {
                int row = wr * (BM / 2) + i * 16 + (lane & 15);
                int off = (ks * 64 + ((lane >> 4) * 16)) ^ ((row & SWM) << 4);
                av[i] = *(const short8v*)(smem + row * RB + off);
            }
            #pragma unroll
            for (int j = 0; j < FJ; ++j) {
                int row = wc * (BN / 2) + j * 16 + (lane & 15);
                int off = (ks * 64 + ((lane >> 4) * 16)) ^ ((row & SWM) << 4);
                bv[j] = *(const short8v*)(smem + TA + row * RB + off);
            }
            #pragma unroll
            for (int i = 0; i < FI; ++i)
                #pragma unroll
                for (int j = 0; j < FJ; ++j)
                    acc[i][j] = __builtin_amdgcn_mfma_f32_16x16x32_bf16(av[i], bv[j], acc[i][j], 0, 0, 0);
        }
        __syncthreads();
    }
    #pragma unroll
    for (int i = 0; i < FI; ++i) {
        #pragma unroll
        for (int j = 0; j < FJ; ++j) {
            int col = n0 + wc * (BN / 2) + j * 16 + (lane & 15);
            int rowb = m0 + wr * (BM / 2) + i * 16 + ((lane >> 4) * 4);
            float bv2 = bias[col];
            #pragma unroll
            for (int v = 0; v < 4; ++v)
                C[(size_t)(rowb + v) * N + col] = f2bf(acc[i][j][v] + bv2);
        }
    }
}

// ---------------- generic act epilogue (bf16 feat): out = center + max_n(theta*support) ----
__global__ __launch_bounds__(256)
void act_kernel(const unsigned short* __restrict__ feat, const int* __restrict__ nbr,
                const float* __restrict__ diffn, const float* __restrict__ dmat,
                unsigned short* __restrict__ outh, int Vv, int OC)
{
    int OC4 = OC >> 2;
    int t = blockIdx.x * 256 + threadIdx.x;
    int total = BS * Vv * OC4;
    if (t >= total) return;
    int c4 = t % OC4;
    int v = (t / OC4) % Vv;
    int b = t / (OC4 * Vv);
    const float4* d4 = (const float4*)dmat;
    float4 D0 = d4[c4], D1 = d4[OC4 + c4], D2 = d4[2 * OC4 + c4];
    float n0 = sqrtf(D0.x * D0.x + D1.x * D1.x + D2.x * D2.x);
    float n1 = sqrtf(D0.y * D0.y + D1.y * D1.y + D2.y * D2.y);
    float n2 = sqrtf(D0.z * D0.z + D1.z * D1.z + D2.z * D2.z);
    float n3 = sqrtf(D0.w * D0.w + D1.w * D1.w + D2.w * D2.w);
    float i0 = 1.0f / fmaxf(n0, 1e-12f);
    float i1 = 1.0f / fmaxf(n1, 1e-12f);
    float i2 = 1.0f / fmaxf(n2, 1e-12f);
    float i3 = 1.0f / fmaxf(n3, 1e-12f);
    D0.x *= i0; D0.y *= i1; D0.z *= i2; D0.w *= i3;
    D1.x *= i0; D1.y *= i1; D1.z *= i2; D1.w *= i3;
    D2.x *= i0; D2.y *= i1; D2.z *= i2; D2.w *= i3;

    const int* nb = nbr + ((size_t)b * Vv + v) * NB;
    const float* dfn = diffn + ((size_t)b * Vv + v) * NB * 3;
    const ushort4* frow = (const ushort4*)feat;
    size_t rowstride = (size_t)(2 * OC4);
    const ushort4* fsup = frow + (size_t)b * Vv * rowstride + OC4 + c4;
    float4 m = make_float4(-FLT_MAX, -FLT_MAX, -FLT_MAX, -FLT_MAX);
    for (int n = 0; n < NB; ++n) {
        int idx = nb[n];
        float e0 = dfn[3 * n + 0], e1 = dfn[3 * n + 1], e2 = dfn[3 * n + 2];
        ushort4 s = fsup[(size_t)idx * rowstride];
        float th;
        th = e0 * D0.x + e1 * D1.x + e2 * D2.x; m.x = fmaxf(m.x, th * bf2f(s.x));
        th = e0 * D0.y + e1 * D1.y + e2 * D2.y; m.y = fmaxf(m.y, th * bf2f(s.y));
        th = e0 * D0.z + e1 * D1.z + e2 * D2.z; m.z = fmaxf(m.z, th * bf2f(s.z));
        th = e0 * D0.w + e1 * D1.w + e2 * D2.w; m.w = fmaxf(m.w, th * bf2f(s.w));
    }
    ushort4 cen = frow[(size_t)b * Vv * rowstride + (size_t)v * rowstride + c4];
    size_t oidx = ((size_t)b * Vv + v) * OC4 + c4;
    ushort4 h;
    h.x = f2bf(bf2f(cen.x) + m.x); h.y = f2bf(bf2f(cen.y) + m.y);
    h.z = f2bf(bf2f(cen.z) + m.z); h.w = f2bf(bf2f(cen.w) + m.w);
    ((ushort4*)outh)[oidx] = h;
}

// ---------------- act for OC=1024 @ V2 with XCD batch-clustering ----------------
// block g -> b=(g&7)>>1 pins batch b to XCD pair {2b,2b+1}; per-batch support (2MB) stays L2.
__global__ __launch_bounds__(256)
void act1024_kernel(const unsigned short* __restrict__ feat, const int* __restrict__ nbr,
                    const float* __restrict__ diffn, const float* __restrict__ dmat,
                    unsigned short* __restrict__ outh)
{
    const int OC4 = 256;
    int g = blockIdx.x;                       // 4096 blocks
    int b = (g & 7) >> 1;
    int v = ((g >> 3) << 1) | (g & 1);
    int c4 = threadIdx.x;                     // 0..255
    const float4* d4 = (const float4*)dmat;
    float4 D0 = d4[c4], D1 = d4[OC4 + c4], D2 = d4[2 * OC4 + c4];
    float n0 = sqrtf(D0.x * D0.x + D1.x * D1.x + D2.x * D2.x);
    float n1 = sqrtf(D0.y * D0.y + D1.y * D1.y + D2.y * D2.y);
    float n2 = sqrtf(D0.z * D0.z + D1.z * D1.z + D2.z * D2.z);
    float n3 = sqrtf(D0.w * D0.w + D1.w * D1.w + D2.w * D2.w);
    float i0 = 1.0f / fmaxf(n0, 1e-12f);
    float i1 = 1.0f / fmaxf(n1, 1e-12f);
    float i2 = 1.0f / fmaxf(n2, 1e-12f);
    float i3 = 1.0f / fmaxf(n3, 1e-12f);
    D0.x *= i0; D0.y *= i1; D0.z *= i2; D0.w *= i3;
    D1.x *= i0; D1.y *= i1; D1.z *= i2; D1.w *= i3;
    D2.x *= i0; D2.y *= i1; D2.z *= i2; D2.w *= i3;

    const int* nb = nbr + ((size_t)b * V2 + v) * NB;
    const float* dfn = diffn + ((size_t)b * V2 + v) * NB * 3;
    const ushort4* frow = (const ushort4*)feat;
    const size_t rowstride = 2 * OC4;         // 512 ushort4 per feat row
    const ushort4* fsup = frow + (size_t)b * V2 * rowstride + OC4 + c4;
    float4 m = make_float4(-FLT_MAX, -FLT_MAX, -FLT_MAX, -FLT_MAX);
    for (int n = 0; n < NB; ++n) {
        int idx = nb[n];
        float e0 = dfn[3 * n + 0], e1 = dfn[3 * n + 1], e2 = dfn[3 * n + 2];
        ushort4 s = fsup[(size_t)idx * rowstride];
        float th;
        th = e0 * D0.x + e1 * D1.x + e2 * D2.x; m.x = fmaxf(m.x, th * bf2f(s.x));
        th = e0 * D0.y + e1 * D1.y + e2 * D2.y; m.y = fmaxf(m.y, th * bf2f(s.y));
        th = e0 * D0.z + e1 * D1.z + e2 * D2.z; m.z = fmaxf(m.z, th * bf2f(s.z));
        th = e0 * D0.w + e1 * D1.w + e2 * D2.w; m.w = fmaxf(m.w, th * bf2f(s.w));
    }
    ushort4 cen = frow[((size_t)b * V2 + v) * rowstride + c4];
    size_t oidx = ((size_t)b * V2 + v) * OC4 + c4;
    ushort4 h;
    h.x = f2bf(bf2f(cen.x) + m.x); h.y = f2bf(bf2f(cen.y) + m.y);
    h.z = f2bf(bf2f(cen.z) + m.z); h.w = f2bf(bf2f(cen.w) + m.w);
    ((ushort4*)outh)[oidx] = h;
}

// ---------------- neighbor max-pool + stride-2 subsample (64 ch, bf16 in/out) ----------------
__global__ __launch_bounds__(256)
void pool_kernel(const ushort4* __restrict__ fmh, const int* __restrict__ nbr,
                 ushort4* __restrict__ outp)
{
    const int C4 = 16;   // 64/4
    int t = blockIdx.x * 256 + threadIdx.x;
    int total = BS * V2 * C4;
    if (t >= total) return;
    int c = t % C4;
    int v2 = (t / C4) % V2;
    int b = t / (C4 * V2);
    const int* nb = nbr + ((size_t)b * V1 + 2 * v2) * NB;
    float4 m = make_float4(-FLT_MAX, -FLT_MAX, -FLT_MAX, -FLT_MAX);
    for (int n = 0; n < NB; ++n) {
        int idx = nb[n];
        ushort4 s = fmh[((size_t)b * V1 + idx) * C4 + c];
        m.x = fmaxf(m.x, bf2f(s.x)); m.y = fmaxf(m.y, bf2f(s.y));
        m.z = fmaxf(m.z, bf2f(s.z)); m.w = fmaxf(m.w, bf2f(s.w));
    }
    ushort4 h;
    h.x = f2bf(m.x); h.y = f2bf(m.y); h.z = f2bf(m.z); h.w = f2bf(m.w);
    outp[((size_t)b * V2 + v2) * C4 + c] = h;
}

// ---------------- global max over vertices, stage 1 (bf16 in, fp32 partials) ------------
__global__ __launch_bounds__(256)
void gmax_part(const unsigned short* __restrict__ fm, float* __restrict__ part)
{
    int c = blockIdx.x * 256 + threadIdx.x;   // 0..1023 (grid.x = 4)
    int ch = blockIdx.y;                      // 0..7
    int b = blockIdx.z;
    float m = -FLT_MAX;
    for (int v = ch * 128; v < (ch + 1) * 128; ++v)
        m = fmaxf(m, bf2f(fm[((size_t)b * V2 + v) * 1024 + c]));
    part[((size_t)b * 8 + ch) * 1024 + c] = m;
}

// ---------------- fc1 split-K partial (gmax finalize fused): hpart[b][kg][j] -------------
__global__ __launch_bounds__(256)
void fc1_part(const float* __restrict__ gpart, const float* __restrict__ fc1w,
              float* __restrict__ hpart)
{
    int b = blockIdx.x, kg = blockIdx.y;    // 4 x 8
    int j = threadIdx.x;                    // 256
    __shared__ float gs[128];
    if (j < 128) {
        float m = -FLT_MAX;
        #pragma unroll
        for (int ch = 0; ch < 8; ++ch)
            m = fmaxf(m, gpart[((size_t)b * 8 + ch) * 1024 + kg * 128 + j]);
        gs[j] = m;
    }
    __syncthreads();
    float h = 0.0f;
    #pragma unroll 4
    for (int k = 0; k < 128; ++k)
        h = fmaf(gs[k], fc1w[(size_t)(kg * 128 + k) * 256 + j], h);
    hpart[((size_t)b * 8 + kg) * 256 + j] = h;
}

// ---------------- head finalize: bn+relu then fc2 ----------------
__global__ __launch_bounds__(256)
void head2_kernel(const float* __restrict__ hpart, const float* __restrict__ fc1b,
                  const float* __restrict__ bng, const float* __restrict__ bnb,
                  const float* __restrict__ fc2w, const float* __restrict__ fc2b,
                  float* __restrict__ outp)
{
    __shared__ float hs[256];
    __shared__ float part[4][40];
    int b = blockIdx.x;
    int j = threadIdx.x;
    float s = fc1b[j];
    #pragma unroll
    for (int kg = 0; kg < 8; ++kg) s += hpart[((size_t)b * 8 + kg) * 256 + j];
    const float rc = 0.99999500003749937f;   // rsqrt(1 + 1e-5)
    s = s * rc * bng[j] + bnb[j];
    hs[j] = fmaxf(s, 0.0f);
    __syncthreads();
    int ks = j >> 6, jo = j & 63;
    if (jo < 40) {
        float o = 0.0f;
        for (int k = ks * 64; k < ks * 64 + 64; ++k)
            o = fmaf(hs[k], fc2w[(size_t)k * 40 + jo], o);
        part[ks][jo] = o;
    }
    __syncthreads();
    if (j < 40)
        outp[(size_t)b * 40 + j] = fc2b[j] + part[0][j] + part[1][j] + part[2][j] + part[3][j];
}

// ---------------- host driver ----------------
extern "C" void kernel_launch(void* const* d_in, const int* in_sizes, int n_in,
                              void* d_out, int out_size, void* d_ws, size_t ws_size,
                              hipStream_t stream)
{
    (void)in_sizes; (void)n_in; (void)out_size; (void)ws_size;
    const float* verts = (const float*)d_in[0];
    auto Wp = [&](int i) { return (const float*)d_in[1 + 3 * i]; };
    auto Bp = [&](int i) { return (const float*)d_in[2 + 3 * i]; };
    auto Dp = [&](int i) { return (const float*)d_in[3 + 3 * i]; };
    const float* fc1w = (const float*)d_in[37];
    const float* fc1b = (const float*)d_in[38];
    const float* bng  = (const float*)d_in[39];
    const float* bnb  = (const float*)d_in[40];
    const float* fc2w = (const float*)d_in[41];
    const float* fc2b = (const float*)d_in[42];

    static const int IC[12] = {3, 32, 64, 64, 64, 64, 64, 128, 256, 1024, 1024, 1024};
    static const int OC[12] = {32, 64, 64, 64, 64, 64, 128, 256, 1024, 1024, 1024, 1024};

    char* ws = (char*)d_ws;
    size_t off = 0;
    auto alloc = [&](size_t bytes) {
        void* p = ws + off;
        off += (bytes + 255) & ~(size_t)255;
        return p;
    };
    int*   nbr1   = (int*)alloc((size_t)BS * V1 * NB * 4);
    int*   nbr2   = (int*)alloc((size_t)BS * V2 * NB * 4);
    float* diffn1 = (float*)alloc((size_t)BS * V1 * NB * 3 * 4);
    float* diffn2 = (float*)alloc((size_t)BS * V2 * NB * 3 * 4);
    unsigned short* feat = (unsigned short*)alloc((size_t)BS * V2 * 2048 * 2);  // 16.8 MB bf16
    unsigned short* fmh0 = (unsigned short*)alloc((size_t)BS * V2 * 1024 * 2);  // 8.4 MB
    unsigned short* fmh1 = (unsigned short*)alloc((size_t)BS * V2 * 1024 * 2);  // 8.4 MB
    float* gpart  = (float*)alloc((size_t)BS * 8 * 1024 * 4);
    float* hpart  = (float*)alloc((size_t)BS * 8 * 256 * 4);

    // bf16 transposed weights per layer (layers 1..11)
    unsigned short* WtBuf[12];
    {
        size_t total = 0;
        for (int i = 1; i < 12; ++i) total += (size_t)(2 * OC[i]) * IC[i];
        unsigned short* base = (unsigned short*)alloc(total * 2);
        size_t o2 = 0;
        for (int i = 1; i < 12; ++i) { WtBuf[i] = base + o2; o2 += (size_t)(2 * OC[i]) * IC[i]; }
    }
    {
        ConvTArgs a;
        int toff = 0;
        for (int i = 1; i < 12; ++i) {
            int K = IC[i], N = 2 * OC[i];
            a.W[i - 1] = Wp(i);
            a.Wt[i - 1] = WtBuf[i];
            a.K[i - 1] = K;
            a.N[i - 1] = N;
            a.tileoff[i - 1] = toff;
            toff += (K / 32) * (N / 32);
        }
        a.tileoff[11] = toff;
        convT_all<<<toff, 256, 0, stream>>>(a);
    }

    auto gemm = [&](const unsigned short* A, int li, unsigned short* Cc, int M) {
        int K = IC[li], N = 2 * OC[li];
        if (N >= 1024) {
            dim3 gdim(N / 128, M / 128);
            gemm_mfma<64, 128, 128><<<gdim, 256, 0, stream>>>(A, WtBuf[li], Bp(li), Cc, M, N, K);
        } else if (K % 64 == 0) {
            dim3 gdim(N / 64, M / 64);
            gemm_mfma<64, 64, 64><<<gdim, 256, 0, stream>>>(A, WtBuf[li], Bp(li), Cc, M, N, K);
        } else {
            dim3 gdim(N / 64, M / 64);
            gemm_mfma<32, 64, 64><<<gdim, 256, 0, stream>>>(A, WtBuf[li], Bp(li), Cc, M, N, K);
        }
    };
    auto act = [&](const unsigned short* f, const int* nbr, const float* dfn, const float* d,
                   unsigned short* outh, int Vv, int oc) {
        if (oc == 1024) {
            act1024_kernel<<<BS * V2, 256, 0, stream>>>(f, nbr, dfn, d, outh);
        } else {
            int total = BS * Vv * (oc / 4);
            act_kernel<<<(total + 255) / 256, 256, 0, stream>>>(f, nbr, dfn, d, outh, Vv, oc);
        }
    };

    // ---- kNN + diffn (fused), both resolutions ----
    knn_wave_kernel<32><<<BS * V1 / 4, 256, 0, stream>>>(verts, 1, nbr1, diffn1);
    knn_wave_kernel<16><<<BS * V2 / 4, 256, 0, stream>>>(verts, 2, nbr2, diffn2);

    // ---- c0 (tiny GEMM, bf16 out) + act ----
    c0_kernel<<<(BS * V1 * 64 + 255) / 256, 256, 0, stream>>>(verts, Wp(0), Bp(0), feat);
    unsigned short* hb[2] = {fmh0, fmh1};
    int pb = 0;
    act(feat, nbr1, diffn1, Dp(0), hb[pb], V1, OC[0]);
    const unsigned short* cur = hb[pb]; pb ^= 1;

    // ---- full-res conv layers (c1, c12, c13, c14, p1) ----
    for (int i = 1; i < 6; ++i) {
        gemm(cur, i, feat, BS * V1);
        act(feat, nbr1, diffn1, Dp(i), hb[pb], V1, OC[i]);
        cur = hb[pb]; pb ^= 1;
    }

    // ---- pool (neighbor max at full res, subsample stride 2, bf16) ----
    {
        int total = BS * V2 * 16;
        pool_kernel<<<(total + 255) / 256, 256, 0, stream>>>(
            (const ushort4*)cur, nbr1, (ushort4*)hb[pb]);
        cur = hb[pb]; pb ^= 1;
    }

    // ---- half-res conv layers (c2, c3, c4, c42, c43, c44) ----
    for (int i = 6; i < 12; ++i) {
        gemm(cur, i, feat, BS * V2);
        act(feat, nbr2, diffn2, Dp(i), hb[pb], V2, OC[i]);
        cur = hb[pb]; pb ^= 1;
    }

    // ---- head (gmax -> fused gmax-final+fc1 split-K -> bn+relu+fc2) ----
    gmax_part<<<dim3(4, 8, BS), 256, 0, stream>>>(cur, gpart);
    fc1_part<<<dim3(BS, 8), 256, 0, stream>>>(gpart, fc1w, hpart);
    head2_kernel<<<BS, 256, 0, stream>>>(hpart, fc1b, bng, bnb, fc2w, fc2b, (float*)d_out);
}

// Round 14
// 506.714 us; speedup vs baseline: 3.9362x; 1.0190x over previous
//
#include <hip/hip_runtime.h>
#include <float.h>
#include <math.h>

#define BS 4
#define V1 2048
#define V2 1024
#define NB 20
#define KSEL 21   // k+1: take 21 nearest, drop the nearest (self)

typedef __attribute__((ext_vector_type(8))) short short8v;   // 8 x bf16 bits (4 VGPRs)
typedef __attribute__((ext_vector_type(4))) float f32x4;

__device__ __forceinline__ unsigned short f2bf(float x) {
    union { float f; unsigned u; } v; v.f = x;
    unsigned r = (v.u + 0x7fffu + ((v.u >> 16) & 1u)) >> 16;   // RNE
    return (unsigned short)r;
}
__device__ __forceinline__ float bf2f(unsigned short h) {
    return __uint_as_float((unsigned)h << 16);
}
__device__ __forceinline__ unsigned umin32(unsigned a, unsigned b) { return a < b ? a : b; }

__device__ __forceinline__ void gload16(const void* g, void* l) {
    __builtin_amdgcn_global_load_lds((const __attribute__((address_space(1))) void*)g,
                                     (__attribute__((address_space(3))) void*)l, 16, 0, 0);
}

// ---------------- kNN + diffn body: one WAVE per query; per-lane sorted top-4 cache ------
// key = (monotonic_dist & ~31) | slot ; candidate j = slot*64 + lane
template<int SLOTS>
__device__ __forceinline__ void knn_body(const float* __restrict__ vb, int stride,
                                         int* __restrict__ nbr, float* __restrict__ diffn,
                                         float* smem, int rel)
{
    constexpr int Vv = SLOTS * 64;
    float* xs = smem;
    float* ys = smem + Vv;
    float* zs = smem + 2 * Vv;
    int tid = threadIdx.x;
    int lane = tid & 63;
    int wv = tid >> 6;                    // wave id 0..3
    int q0 = rel * 4;
    for (int p = tid; p < Vv; p += 256) {
        xs[p] = vb[(size_t)p * stride * 3 + 0];
        ys[p] = vb[(size_t)p * stride * 3 + 1];
        zs[p] = vb[(size_t)p * stride * 3 + 2];
    }
    __syncthreads();
    int i = q0 + wv;                      // this wave's query
    float xi = xs[i], yi = ys[i], zi = zs[i];
    float sqi = xi * xi + yi * yi + zi * zi;
    unsigned keys[SLOTS];
    #pragma unroll
    for (int s = 0; s < SLOTS; ++s) {
        int j = s * 64 + lane;
        float xj = xs[j], yj = ys[j], zj = zs[j];
        float sqj = xj * xj + yj * yj + zj * zj;
        float d = sqi - 2.0f * (xi * xj + yi * yj + zi * zj) + sqj;
        unsigned u = __float_as_uint(d);
        u = (u & 0x80000000u) ? ~u : (u | 0x80000000u);
        keys[s] = (u & ~31u) | (unsigned)s;
    }
    const unsigned UMAX = 0xFFFFFFFFu;
    unsigned c0 = UMAX, c1 = UMAX, c2 = UMAX, c3 = UMAX;
    #pragma unroll
    for (int s = 0; s < SLOTS; ++s) c0 = umin32(c0, keys[s]);
    #pragma unroll
    for (int s = 0; s < SLOTS; ++s) { unsigned k = keys[s]; if (k > c0) c1 = umin32(c1, k); }
    #pragma unroll
    for (int s = 0; s < SLOTS; ++s) { unsigned k = keys[s]; if (k > c1) c2 = umin32(c2, k); }
    #pragma unroll
    for (int s = 0; s < SLOTS; ++s) { unsigned k = keys[s]; if (k > c2) c3 = umin32(c3, k); }

    unsigned lm = c0;
    int myj = 0;
    for (int it = 0; it < KSEL; ++it) {
        unsigned m = lm;
        #pragma unroll
        for (int off = 1; off < 64; off <<= 1)
            m = umin32(m, (unsigned)__shfl_xor((int)m, off));
        unsigned long long bal = __ballot(lm == m);
        int wl = __ffsll(bal) - 1;
        int slot = (int)(m & 31u);
        int j = slot * 64 + wl;
        if (lane == it - 1) myj = j;               // lanes 0..19 capture winners 1..20
        if (lane == wl) {
            c0 = c1; c1 = c2; c2 = c3; c3 = UMAX;  // pop head
            if (c0 == UMAX) {                      // rare refill
                #pragma unroll
                for (int s = 0; s < SLOTS; ++s) {
                    unsigned k = keys[s];
                    if (k > m) c0 = umin32(c0, k);
                }
            }
            lm = c0;
        }
    }
    if (lane < NB) {
        nbr[(size_t)i * NB + lane] = myj;
        float dx = xs[myj] - xi, dy = ys[myj] - yi, dz = zs[myj] - zi;
        float nrm = sqrtf(dx * dx + dy * dy + dz * dz);
        float inv = 1.0f / fmaxf(nrm, 1e-12f);
        float* dout = diffn + ((size_t)i * NB + lane) * 3;
        dout[0] = dx * inv; dout[1] = dy * inv; dout[2] = dz * inv;
    }
}

// single dispatch for both resolutions: blocks [0, BS*V1/4) = V1, rest = V2
__global__ __launch_bounds__(256)
void knn_all_kernel(const float* __restrict__ verts,
                    int* __restrict__ nbr1, float* __restrict__ diffn1,
                    int* __restrict__ nbr2, float* __restrict__ diffn2)
{
    __shared__ float smem[3 * V1];
    int g = blockIdx.x;
    if (g < BS * V1 / 4) {
        int b = g / (V1 / 4), rel = g % (V1 / 4);
        knn_body<32>(verts + (size_t)b * V1 * 3, 1,
                     nbr1 + (size_t)b * V1 * NB, diffn1 + (size_t)b * V1 * NB * 3,
                     smem, rel);
    } else {
        int g2 = g - BS * V1 / 4;
        int b = g2 / (V2 / 4), rel = g2 % (V2 / 4);
        knn_body<16>(verts + (size_t)b * V1 * 3, 2,
                     nbr2 + (size_t)b * V2 * NB, diffn2 + (size_t)b * V2 * NB * 3,
                     smem, rel);
    }
}

// ---------------- fused weight transpose + fp32->bf16 for all 11 layers ----------------
struct ConvTArgs {
    const float* W[11];
    unsigned short* Wt[11];
    int K[11];
    int N[11];
    int tileoff[12];
};

__global__ __launch_bounds__(256)
void convT_all(ConvTArgs a)
{
    __shared__ float t[32][33];
    int g = blockIdx.x;
    int L = 0;
    #pragma unroll
    for (int q = 0; q < 10; ++q) if (g >= a.tileoff[q + 1]) L = q + 1;
    int rel = g - a.tileoff[L];
    int K = a.K[L], N = a.N[L];
    int tilesN = N >> 5;
    int k0 = (rel / tilesN) << 5, n0 = (rel % tilesN) << 5;
    const float* W = a.W[L];
    unsigned short* Wt = a.Wt[L];
    int tx = threadIdx.x & 31, ty = threadIdx.x >> 5;   // ty 0..7
    #pragma unroll
    for (int r = ty; r < 32; r += 8) t[r][tx] = W[(size_t)(k0 + r) * N + n0 + tx];
    __syncthreads();
    #pragma unroll
    for (int r = ty; r < 32; r += 8) Wt[(size_t)(n0 + r) * K + k0 + tx] = f2bf(t[tx][r]);
}

// ---------------- act0: c0 GEMM (3->64) folded into the act epilogue, bf16 out ----------
// OC=32, OC4=8. Per neighbor, support channels recomputed from verts (12 fma) instead of
// gathering precomputed feat. Center computed from own vertex. No feat0 buffer at all.
__global__ __launch_bounds__(256)
void act0_kernel(const float* __restrict__ verts, const float* __restrict__ W,
                 const float* __restrict__ Bv, const float* __restrict__ dmat,
                 const int* __restrict__ nbr, const float* __restrict__ diffn,
                 unsigned short* __restrict__ outh)
{
    int t = blockIdx.x * 256 + threadIdx.x;     // total BS*V1*8 = 65536
    int c4 = t & 7;
    int v = (t >> 3) & (V1 - 1);
    int b = t >> 14;
    const float4* d4 = (const float4*)dmat;     // 3 x 32
    float4 D0 = d4[c4], D1 = d4[8 + c4], D2 = d4[16 + c4];
    float n0 = sqrtf(D0.x * D0.x + D1.x * D1.x + D2.x * D2.x);
    float n1 = sqrtf(D0.y * D0.y + D1.y * D1.y + D2.y * D2.y);
    float n2 = sqrtf(D0.z * D0.z + D1.z * D1.z + D2.z * D2.z);
    float n3 = sqrtf(D0.w * D0.w + D1.w * D1.w + D2.w * D2.w);
    float i0 = 1.0f / fmaxf(n0, 1e-12f);
    float i1 = 1.0f / fmaxf(n1, 1e-12f);
    float i2 = 1.0f / fmaxf(n2, 1e-12f);
    float i3 = 1.0f / fmaxf(n3, 1e-12f);
    D0.x *= i0; D0.y *= i1; D0.z *= i2; D0.w *= i3;
    D1.x *= i0; D1.y *= i1; D1.z *= i2; D1.w *= i3;
    D2.x *= i0; D2.y *= i1; D2.z *= i2; D2.w *= i3;
    float dA[4] = {D0.x, D0.y, D0.z, D0.w};
    float dB[4] = {D1.x, D1.y, D1.z, D1.w};
    float dC[4] = {D2.x, D2.y, D2.z, D2.w};

    // weight columns: W is 3 x 64 row-major; center cols [0,32), support cols [32,64)
    float wcx[4], wcy[4], wcz[4], wsx[4], wsy[4], wsz[4], bc[4], bs[4];
    #pragma unroll
    for (int j = 0; j < 4; ++j) {
        int cc = c4 * 4 + j;
        wcx[j] = W[cc];       wcy[j] = W[64 + cc];       wcz[j] = W[128 + cc];
        wsx[j] = W[32 + cc];  wsy[j] = W[96 + cc];       wsz[j] = W[160 + cc];
        bc[j] = Bv[cc];       bs[j] = Bv[32 + cc];
    }
    const float* vb = verts + (size_t)b * V1 * 3;
    float xv = vb[(size_t)v * 3 + 0];
    float yv = vb[(size_t)v * 3 + 1];
    float zv = vb[(size_t)v * 3 + 2];
    const int* nb_ = nbr + ((size_t)b * V1 + v) * NB;
    const float* dfn = diffn + ((size_t)b * V1 + v) * NB * 3;
    float m[4] = {-FLT_MAX, -FLT_MAX, -FLT_MAX, -FLT_MAX};
    for (int n = 0; n < NB; ++n) {
        int idx = nb_[n];
        float e0 = dfn[3 * n + 0], e1 = dfn[3 * n + 1], e2 = dfn[3 * n + 2];
        float xn = vb[(size_t)idx * 3 + 0];
        float yn = vb[(size_t)idx * 3 + 1];
        float zn = vb[(size_t)idx * 3 + 2];
        #pragma unroll
        for (int j = 0; j < 4; ++j) {
            float sup = xn * wsx[j] + yn * wsy[j] + zn * wsz[j] + bs[j];
            float th = e0 * dA[j] + e1 * dB[j] + e2 * dC[j];
            m[j] = fmaxf(m[j], th * sup);
        }
    }
    ushort4 h;
    h.x = f2bf(xv * wcx[0] + yv * wcy[0] + zv * wcz[0] + bc[0] + m[0]);
    h.y = f2bf(xv * wcx[1] + yv * wcy[1] + zv * wcz[1] + bc[1] + m[1]);
    h.z = f2bf(xv * wcx[2] + yv * wcy[2] + zv * wcz[2] + bc[2] + m[2]);
    h.w = f2bf(xv * wcx[3] + yv * wcy[3] + zv * wcz[3] + bc[3] + m[3]);
    ((ushort4*)outh)[((size_t)b * V1 + v) * 8 + c4] = h;
}

// ---------------- bf16 MFMA GEMM + bias: C(MxN bf16) = A(MxK) @ Wt(NxK)^T + bias --------
// 4 waves (2x2); per-wave tile (BM/2)x(BN/2); XCD-chunked block swizzle (T1).
template<int BK, int BM, int BN>
__global__ __launch_bounds__(256)
void gemm_mfma(const unsigned short* __restrict__ A, const unsigned short* __restrict__ Wt,
               const float* __restrict__ bias, unsigned short* __restrict__ C,
               int M, int N, int K)
{
    constexpr int RB = BK * 2;               // row bytes
    constexpr int TA = BM * RB;
    constexpr int TB = BN * RB;
    constexpr int SWM = (BK == 64) ? 7 : 3;  // swizzle row mask
    constexpr int FI = BM / 32, FJ = BN / 32;
    constexpr int RA = TA / 4096, RBN = TB / 4096;
    constexpr int RMAX = (RA > RBN) ? RA : RBN;
    __shared__ __align__(16) char smem[TA + TB];
    int tid = threadIdx.x;
    int lane = tid & 63, wid = tid >> 6;
    int wr = wid >> 1, wc = wid & 1;

    // T1: bijective chunked XCD swizzle (all our grids have nwg % 8 == 0)
    int nwg = gridDim.x * gridDim.y;
    int orig = blockIdx.y * gridDim.x + blockIdx.x;
    int wg = orig;
    if ((nwg & 7) == 0) wg = (orig & 7) * (nwg >> 3) + (orig >> 3);
    int m0 = (wg / gridDim.x) * BM;
    int n0 = (wg % gridDim.x) * BN;

    f32x4 acc[FI][FJ] = {};

    int srow[RMAX], soffe[RMAX];
    #pragma unroll
    for (int r = 0; r < RMAX; ++r) {
        int L = r * 4096 + tid * 16;
        int row = L / RB;
        int off = (L % RB) ^ ((row & SWM) << 4);
        srow[r] = row; soffe[r] = off >> 1;
    }

    for (int kt = 0; kt < K; kt += BK) {
        #pragma unroll
        for (int r = 0; r < RA; ++r)
            gload16(A + (size_t)(m0 + srow[r]) * K + kt + soffe[r],
                    smem + r * 4096 + wid * 1024);
        #pragma unroll
        for (int r = 0; r < RBN; ++r)
            gload16(Wt + (size_t)(n0 + srow[r]) * K + kt + soffe[r],
                    smem + TA + r * 4096 + wid * 1024);
        asm volatile("s_waitcnt vmcnt(0)" ::: "memory");
        __syncthreads();
        #pragma unroll
        for (int ks = 0; ks < BK / 32; ++ks) {
            short8v av[FI], bv[FJ];
            #pragma unroll
            for (int i = 0; i < FI; ++i) {
                int row = wr * (BM / 2) + i * 16 + (lane & 15);
                int off = (ks * 64 + ((lane >> 4) * 16)) ^ ((row & SWM) << 4);
                av[i] = *(const short8v*)(smem + row * RB + off);
            }
            #pragma unroll
            for (int j = 0; j < FJ; ++j) {
                int row = wc * (BN / 2) + j * 16 + (lane & 15);
                int off = (ks * 64 + ((lane >> 4) * 16)) ^ ((row & SWM) << 4);
                bv[j] = *(const short8v*)(smem + TA + row * RB + off);
            }
            #pragma unroll
            for (int i = 0; i < FI; ++i)
                #pragma unroll
                for (int j = 0; j < FJ; ++j)
                    acc[i][j] = __builtin_amdgcn_mfma_f32_16x16x32_bf16(av[i], bv[j], acc[i][j], 0, 0, 0);
        }
        __syncthreads();
    }
    #pragma unroll
    for (int i = 0; i < FI; ++i) {
        #pragma unroll
        for (int j = 0; j < FJ; ++j) {
            int col = n0 + wc * (BN / 2) + j * 16 + (lane & 15);
            int rowb = m0 + wr * (BM / 2) + i * 16 + ((lane >> 4) * 4);
            float bv2 = bias[col];
            #pragma unroll
            for (int v = 0; v < 4; ++v)
                C[(size_t)(rowb + v) * N + col] = f2bf(acc[i][j][v] + bv2);
        }
    }
}

// ---------------- generic act epilogue (bf16 feat): out = center + max_n(theta*support) ----
__global__ __launch_bounds__(256)
void act_kernel(const unsigned short* __restrict__ feat, const int* __restrict__ nbr,
                const float* __restrict__ diffn, const float* __restrict__ dmat,
                unsigned short* __restrict__ outh, int Vv, int OC)
{
    int OC4 = OC >> 2;
    int t = blockIdx.x * 256 + threadIdx.x;
    int total = BS * Vv * OC4;
    if (t >= total) return;
    int c4 = t % OC4;
    int v = (t / OC4) % Vv;
    int b = t / (OC4 * Vv);
    const float4* d4 = (const float4*)dmat;
    float4 D0 = d4[c4], D1 = d4[OC4 + c4], D2 = d4[2 * OC4 + c4];
    float n0 = sqrtf(D0.x * D0.x + D1.x * D1.x + D2.x * D2.x);
    float n1 = sqrtf(D0.y * D0.y + D1.y * D1.y + D2.y * D2.y);
    float n2 = sqrtf(D0.z * D0.z + D1.z * D1.z + D2.z * D2.z);
    float n3 = sqrtf(D0.w * D0.w + D1.w * D1.w + D2.w * D2.w);
    float i0 = 1.0f / fmaxf(n0, 1e-12f);
    float i1 = 1.0f / fmaxf(n1, 1e-12f);
    float i2 = 1.0f / fmaxf(n2, 1e-12f);
    float i3 = 1.0f / fmaxf(n3, 1e-12f);
    D0.x *= i0; D0.y *= i1; D0.z *= i2; D0.w *= i3;
    D1.x *= i0; D1.y *= i1; D1.z *= i2; D1.w *= i3;
    D2.x *= i0; D2.y *= i1; D2.z *= i2; D2.w *= i3;

    const int* nb = nbr + ((size_t)b * Vv + v) * NB;
    const float* dfn = diffn + ((size_t)b * Vv + v) * NB * 3;
    const ushort4* frow = (const ushort4*)feat;
    size_t rowstride = (size_t)(2 * OC4);
    const ushort4* fsup = frow + (size_t)b * Vv * rowstride + OC4 + c4;
    float4 m = make_float4(-FLT_MAX, -FLT_MAX, -FLT_MAX, -FLT_MAX);
    for (int n = 0; n < NB; ++n) {
        int idx = nb[n];
        float e0 = dfn[3 * n + 0], e1 = dfn[3 * n + 1], e2 = dfn[3 * n + 2];
        ushort4 s = fsup[(size_t)idx * rowstride];
        float th;
        th = e0 * D0.x + e1 * D1.x + e2 * D2.x; m.x = fmaxf(m.x, th * bf2f(s.x));
        th = e0 * D0.y + e1 * D1.y + e2 * D2.y; m.y = fmaxf(m.y, th * bf2f(s.y));
        th = e0 * D0.z + e1 * D1.z + e2 * D2.z; m.z = fmaxf(m.z, th * bf2f(s.z));
        th = e0 * D0.w + e1 * D1.w + e2 * D2.w; m.w = fmaxf(m.w, th * bf2f(s.w));
    }
    ushort4 cen = frow[(size_t)b * Vv * rowstride + (size_t)v * rowstride + c4];
    size_t oidx = ((size_t)b * Vv + v) * OC4 + c4;
    ushort4 h;
    h.x = f2bf(bf2f(cen.x) + m.x); h.y = f2bf(bf2f(cen.y) + m.y);
    h.z = f2bf(bf2f(cen.z) + m.z); h.w = f2bf(bf2f(cen.w) + m.w);
    ((ushort4*)outh)[oidx] = h;
}

// ---------------- act for OC=1024 @ V2 with XCD batch-clustering ----------------
// block g -> b=(g&7)>>1 pins batch b to XCD pair {2b,2b+1}; per-batch support (2MB) stays L2.
__global__ __launch_bounds__(256)
void act1024_kernel(const unsigned short* __restrict__ feat, const int* __restrict__ nbr,
                    const float* __restrict__ diffn, const float* __restrict__ dmat,
                    unsigned short* __restrict__ outh)
{
    const int OC4 = 256;
    int g = blockIdx.x;                       // 4096 blocks
    int b = (g & 7) >> 1;
    int v = ((g >> 3) << 1) | (g & 1);
    int c4 = threadIdx.x;                     // 0..255
    const float4* d4 = (const float4*)dmat;
    float4 D0 = d4[c4], D1 = d4[OC4 + c4], D2 = d4[2 * OC4 + c4];
    float n0 = sqrtf(D0.x * D0.x + D1.x * D1.x + D2.x * D2.x);
    float n1 = sqrtf(D0.y * D0.y + D1.y * D1.y + D2.y * D2.y);
    float n2 = sqrtf(D0.z * D0.z + D1.z * D1.z + D2.z * D2.z);
    float n3 = sqrtf(D0.w * D0.w + D1.w * D1.w + D2.w * D2.w);
    float i0 = 1.0f / fmaxf(n0, 1e-12f);
    float i1 = 1.0f / fmaxf(n1, 1e-12f);
    float i2 = 1.0f / fmaxf(n2, 1e-12f);
    float i3 = 1.0f / fmaxf(n3, 1e-12f);
    D0.x *= i0; D0.y *= i1; D0.z *= i2; D0.w *= i3;
    D1.x *= i0; D1.y *= i1; D1.z *= i2; D1.w *= i3;
    D2.x *= i0; D2.y *= i1; D2.z *= i2; D2.w *= i3;

    const int* nb = nbr + ((size_t)b * V2 + v) * NB;
    const float* dfn = diffn + ((size_t)b * V2 + v) * NB * 3;
    const ushort4* frow = (const ushort4*)feat;
    const size_t rowstride = 2 * OC4;         // 512 ushort4 per feat row
    const ushort4* fsup = frow + (size_t)b * V2 * rowstride + OC4 + c4;
    float4 m = make_float4(-FLT_MAX, -FLT_MAX, -FLT_MAX, -FLT_MAX);
    for (int n = 0; n < NB; ++n) {
        int idx = nb[n];
        float e0 = dfn[3 * n + 0], e1 = dfn[3 * n + 1], e2 = dfn[3 * n + 2];
        ushort4 s = fsup[(size_t)idx * rowstride];
        float th;
        th = e0 * D0.x + e1 * D1.x + e2 * D2.x; m.x = fmaxf(m.x, th * bf2f(s.x));
        th = e0 * D0.y + e1 * D1.y + e2 * D2.y; m.y = fmaxf(m.y, th * bf2f(s.y));
        th = e0 * D0.z + e1 * D1.z + e2 * D2.z; m.z = fmaxf(m.z, th * bf2f(s.z));
        th = e0 * D0.w + e1 * D1.w + e2 * D2.w; m.w = fmaxf(m.w, th * bf2f(s.w));
    }
    ushort4 cen = frow[((size_t)b * V2 + v) * rowstride + c4];
    size_t oidx = ((size_t)b * V2 + v) * OC4 + c4;
    ushort4 h;
    h.x = f2bf(bf2f(cen.x) + m.x); h.y = f2bf(bf2f(cen.y) + m.y);
    h.z = f2bf(bf2f(cen.z) + m.z); h.w = f2bf(bf2f(cen.w) + m.w);
    ((ushort4*)outh)[oidx] = h;
}

// ---------------- neighbor max-pool + stride-2 subsample (64 ch, bf16 in/out) ----------------
__global__ __launch_bounds__(256)
void pool_kernel(const ushort4* __restrict__ fmh, const int* __restrict__ nbr,
                 ushort4* __restrict__ outp)
{
    const int C4 = 16;   // 64/4
    int t = blockIdx.x * 256 + threadIdx.x;
    int total = BS * V2 * C4;
    if (t >= total) return;
    int c = t % C4;
    int v2 = (t / C4) % V2;
    int b = t / (C4 * V2);
    const int* nb = nbr + ((size_t)b * V1 + 2 * v2) * NB;
    float4 m = make_float4(-FLT_MAX, -FLT_MAX, -FLT_MAX, -FLT_MAX);
    for (int n = 0; n < NB; ++n) {
        int idx = nb[n];
        ushort4 s = fmh[((size_t)b * V1 + idx) * C4 + c];
        m.x = fmaxf(m.x, bf2f(s.x)); m.y = fmaxf(m.y, bf2f(s.y));
        m.z = fmaxf(m.z, bf2f(s.z)); m.w = fmaxf(m.w, bf2f(s.w));
    }
    ushort4 h;
    h.x = f2bf(m.x); h.y = f2bf(m.y); h.z = f2bf(m.z); h.w = f2bf(m.w);
    outp[((size_t)b * V2 + v2) * C4 + c] = h;
}

// ---------------- global max over vertices, stage 1 (bf16 in, fp32 partials) ------------
__global__ __launch_bounds__(256)
void gmax_part(const unsigned short* __restrict__ fm, float* __restrict__ part)
{
    int c = blockIdx.x * 256 + threadIdx.x;   // 0..1023 (grid.x = 4)
    int ch = blockIdx.y;                      // 0..7
    int b = blockIdx.z;
    float m = -FLT_MAX;
    for (int v = ch * 128; v < (ch + 1) * 128; ++v)
        m = fmaxf(m, bf2f(fm[((size_t)b * V2 + v) * 1024 + c]));
    part[((size_t)b * 8 + ch) * 1024 + c] = m;
}

// ---------------- fc1 split-K partial (gmax finalize fused): hpart[b][kg][j] -------------
__global__ __launch_bounds__(256)
void fc1_part(const float* __restrict__ gpart, const float* __restrict__ fc1w,
              float* __restrict__ hpart)
{
    int b = blockIdx.x, kg = blockIdx.y;    // 4 x 8
    int j = threadIdx.x;                    // 256
    __shared__ float gs[128];
    if (j < 128) {
        float m = -FLT_MAX;
        #pragma unroll
        for (int ch = 0; ch < 8; ++ch)
            m = fmaxf(m, gpart[((size_t)b * 8 + ch) * 1024 + kg * 128 + j]);
        gs[j] = m;
    }
    __syncthreads();
    float h = 0.0f;
    #pragma unroll 4
    for (int k = 0; k < 128; ++k)
        h = fmaf(gs[k], fc1w[(size_t)(kg * 128 + k) * 256 + j], h);
    hpart[((size_t)b * 8 + kg) * 256 + j] = h;
}

// ---------------- head finalize: bn+relu then fc2 ----------------
__global__ __launch_bounds__(256)
void head2_kernel(const float* __restrict__ hpart, const float* __restrict__ fc1b,
                  const float* __restrict__ bng, const float* __restrict__ bnb,
                  const float* __restrict__ fc2w, const float* __restrict__ fc2b,
                  float* __restrict__ outp)
{
    __shared__ float hs[256];
    __shared__ float part[4][40];
    int b = blockIdx.x;
    int j = threadIdx.x;
    float s = fc1b[j];
    #pragma unroll
    for (int kg = 0; kg < 8; ++kg) s += hpart[((size_t)b * 8 + kg) * 256 + j];
    const float rc = 0.99999500003749937f;   // rsqrt(1 + 1e-5)
    s = s * rc * bng[j] + bnb[j];
    hs[j] = fmaxf(s, 0.0f);
    __syncthreads();
    int ks = j >> 6, jo = j & 63;
    if (jo < 40) {
        float o = 0.0f;
        for (int k = ks * 64; k < ks * 64 + 64; ++k)
            o = fmaf(hs[k], fc2w[(size_t)k * 40 + jo], o);
        part[ks][jo] = o;
    }
    __syncthreads();
    if (j < 40)
        outp[(size_t)b * 40 + j] = fc2b[j] + part[0][j] + part[1][j] + part[2][j] + part[3][j];
}

// ---------------- host driver ----------------
extern "C" void kernel_launch(void* const* d_in, const int* in_sizes, int n_in,
                              void* d_out, int out_size, void* d_ws, size_t ws_size,
                              hipStream_t stream)
{
    (void)in_sizes; (void)n_in; (void)out_size; (void)ws_size;
    const float* verts = (const float*)d_in[0];
    auto Wp = [&](int i) { return (const float*)d_in[1 + 3 * i]; };
    auto Bp = [&](int i) { return (const float*)d_in[2 + 3 * i]; };
    auto Dp = [&](int i) { return (const float*)d_in[3 + 3 * i]; };
    const float* fc1w = (const float*)d_in[37];
    const float* fc1b = (const float*)d_in[38];
    const float* bng  = (const float*)d_in[39];
    const float* bnb  = (const float*)d_in[40];
    const float* fc2w = (const float*)d_in[41];
    const float* fc2b = (const float*)d_in[42];

    static const int IC[12] = {3, 32, 64, 64, 64, 64, 64, 128, 256, 1024, 1024, 1024};
    static const int OC[12] = {32, 64, 64, 64, 64, 64, 128, 256, 1024, 1024, 1024, 1024};

    char* ws = (char*)d_ws;
    size_t off = 0;
    auto alloc = [&](size_t bytes) {
        void* p = ws + off;
        off += (bytes + 255) & ~(size_t)255;
        return p;
    };
    int*   nbr1   = (int*)alloc((size_t)BS * V1 * NB * 4);
    int*   nbr2   = (int*)alloc((size_t)BS * V2 * NB * 4);
    float* diffn1 = (float*)alloc((size_t)BS * V1 * NB * 3 * 4);
    float* diffn2 = (float*)alloc((size_t)BS * V2 * NB * 3 * 4);
    unsigned short* feat = (unsigned short*)alloc((size_t)BS * V2 * 2048 * 2);  // 16.8 MB bf16
    unsigned short* fmh0 = (unsigned short*)alloc((size_t)BS * V2 * 1024 * 2);  // 8.4 MB
    unsigned short* fmh1 = (unsigned short*)alloc((size_t)BS * V2 * 1024 * 2);  // 8.4 MB
    float* gpart  = (float*)alloc((size_t)BS * 8 * 1024 * 4);
    float* hpart  = (float*)alloc((size_t)BS * 8 * 256 * 4);

    // bf16 transposed weights per layer (layers 1..11)
    unsigned short* WtBuf[12];
    {
        size_t total = 0;
        for (int i = 1; i < 12; ++i) total += (size_t)(2 * OC[i]) * IC[i];
        unsigned short* base = (unsigned short*)alloc(total * 2);
        size_t o2 = 0;
        for (int i = 1; i < 12; ++i) { WtBuf[i] = base + o2; o2 += (size_t)(2 * OC[i]) * IC[i]; }
    }
    {
        ConvTArgs a;
        int toff = 0;
        for (int i = 1; i < 12; ++i) {
            int K = IC[i], N = 2 * OC[i];
            a.W[i - 1] = Wp(i);
            a.Wt[i - 1] = WtBuf[i];
            a.K[i - 1] = K;
            a.N[i - 1] = N;
            a.tileoff[i - 1] = toff;
            toff += (K / 32) * (N / 32);
        }
        a.tileoff[11] = toff;
        convT_all<<<toff, 256, 0, stream>>>(a);
    }

    auto gemm = [&](const unsigned short* A, int li, unsigned short* Cc, int M) {
        int K = IC[li], N = 2 * OC[li];
        if (N >= 1024) {
            dim3 gdim(N / 128, M / 128);
            gemm_mfma<64, 128, 128><<<gdim, 256, 0, stream>>>(A, WtBuf[li], Bp(li), Cc, M, N, K);
        } else if (K % 64 == 0) {
            dim3 gdim(N / 64, M / 64);
            gemm_mfma<64, 64, 64><<<gdim, 256, 0, stream>>>(A, WtBuf[li], Bp(li), Cc, M, N, K);
        } else {
            dim3 gdim(N / 64, M / 64);
            gemm_mfma<32, 64, 64><<<gdim, 256, 0, stream>>>(A, WtBuf[li], Bp(li), Cc, M, N, K);
        }
    };
    auto act = [&](const unsigned short* f, const int* nbr, const float* dfn, const float* d,
                   unsigned short* outh, int Vv, int oc) {
        if (oc == 1024) {
            act1024_kernel<<<BS * V2, 256, 0, stream>>>(f, nbr, dfn, d, outh);
        } else {
            int total = BS * Vv * (oc / 4);
            act_kernel<<<(total + 255) / 256, 256, 0, stream>>>(f, nbr, dfn, d, outh, Vv, oc);
        }
    };

    // ---- kNN + diffn (fused), both resolutions in ONE dispatch ----
    knn_all_kernel<<<BS * V1 / 4 + BS * V2 / 4, 256, 0, stream>>>(
        verts, nbr1, diffn1, nbr2, diffn2);

    // ---- layer 0: c0 GEMM folded into act0 (no feat0 materialization) ----
    unsigned short* hb[2] = {fmh0, fmh1};
    int pb = 0;
    act0_kernel<<<BS * V1 * 8 / 256, 256, 0, stream>>>(
        verts, Wp(0), Bp(0), Dp(0), nbr1, diffn1, hb[pb]);
    const unsigned short* cur = hb[pb]; pb ^= 1;

    // ---- full-res conv layers (c1, c12, c13, c14, p1) ----
    for (int i = 1; i < 6; ++i) {
        gemm(cur, i, feat, BS * V1);
        act(feat, nbr1, diffn1, Dp(i), hb[pb], V1, OC[i]);
        cur = hb[pb]; pb ^= 1;
    }

    // ---- pool (neighbor max at full res, subsample stride 2, bf16) ----
    {
        int total = BS * V2 * 16;
        pool_kernel<<<(total + 255) / 256, 256, 0, stream>>>(
            (const ushort4*)cur, nbr1, (ushort4*)hb[pb]);
        cur = hb[pb]; pb ^= 1;
    }

    // ---- half-res conv layers (c2, c3, c4, c42, c43, c44) ----
    for (int i = 6; i < 12; ++i) {
        gemm(cur, i, feat, BS * V2);
        act(feat, nbr2, diffn2, Dp(i), hb[pb], V2, OC[i]);
        cur = hb[pb]; pb ^= 1;
    }

    // ---- head (gmax -> fused gmax-final+fc1 split-K -> bn+relu+fc2) ----
    gmax_part<<<dim3(4, 8, BS), 256, 0, stream>>>(cur, gpart);
    fc1_part<<<dim3(BS, 8), 256, 0, stream>>>(gpart, fc1w, hpart);
    head2_kernel<<<BS, 256, 0, stream>>>(hpart, fc1b, bng, bnb, fc2w, fc2b, (float*)d_out);
}